// Round 18
// baseline (239.571 us; speedup 1.0000x reference)
//
#include <hip/hip_runtime.h>

typedef __attribute__((ext_vector_type(8))) short s16x8;
typedef __attribute__((ext_vector_type(4))) short s16x4;
typedef __attribute__((ext_vector_type(4))) float f32x4;

static __device__ __forceinline__ short f2bf(float f) {
    unsigned u = __builtin_bit_cast(unsigned, f);
    u = (u + 0x7FFFu + ((u >> 16) & 1u)) >> 16;
    return (short)u;
}

__device__ __forceinline__ void gload16(const short* g, short* l) {
    __builtin_amdgcn_global_load_lds(
        (const __attribute__((address_space(1))) void*)g,
        (__attribute__((address_space(3))) void*)l,
        16, 0, 0);
}

// ---------------- prep: LN1 rows + all 4 weight transposes in ONE launch
__device__ __forceinline__ void tc_tile(
    const float* __restrict__ W, short* __restrict__ Wt, int K, int N,
    int bx, int by, int tx, int ty)
{
    __shared__ float tile[32][33];
    for (int i = 0; i < 32; i += 8)
        tile[ty + i][tx] = W[(size_t)(by + ty + i) * N + bx + tx];
    __syncthreads();
    for (int i = 0; i < 32; i += 8)
        Wt[(size_t)(bx + ty + i) * K + by + tx] = f2bf(tile[tx][ty + i]);
}

__device__ __forceinline__ void ln_row(
    const float* __restrict__ x, const float* __restrict__ g,
    const float* __restrict__ b, short* __restrict__ out, int row, int t)
{
    __shared__ float red[4];
    const float* xr = x + (size_t)row * 768;
    float v0 = xr[t], v1 = xr[t + 256], v2 = xr[t + 512];
    float s = v0 + v1 + v2;
    for (int off = 32; off >= 1; off >>= 1) s += __shfl_down(s, off, 64);
    if ((t & 63) == 0) red[t >> 6] = s;
    __syncthreads();
    const float mean = (red[0] + red[1] + red[2] + red[3]) * (1.0f / 768.0f);
    const float d0 = v0 - mean, d1 = v1 - mean, d2 = v2 - mean;
    __syncthreads();
    float ss = d0 * d0 + d1 * d1 + d2 * d2;
    for (int off = 32; off >= 1; off >>= 1) ss += __shfl_down(ss, off, 64);
    if ((t & 63) == 0) red[t >> 6] = ss;
    __syncthreads();
    const float var = (red[0] + red[1] + red[2] + red[3]) * (1.0f / 768.0f);
    const float rstd = rsqrtf(var + 1e-5f);
    out[(size_t)row * 768 + t]       = f2bf(d0 * rstd * g[t] + b[t]);
    out[(size_t)row * 768 + t + 256] = f2bf(d1 * rstd * g[t + 256] + b[t + 256]);
    out[(size_t)row * 768 + t + 512] = f2bf(d2 * rstd * g[t + 512] + b[t + 512]);
}

// blocks: 0..8191 LN1 | then qkv 1728 | proj 576 | fc1 2304 | fc2 2304
__global__ __launch_bounds__(256) void prep_all(
    const float* __restrict__ x, const float* __restrict__ n1g,
    const float* __restrict__ n1b, short* __restrict__ ln_out,
    const float* __restrict__ qkv_w, const float* __restrict__ proj_w,
    const float* __restrict__ fc1_w, const float* __restrict__ fc2_w,
    short* __restrict__ qkv_wT, short* __restrict__ proj_wT,
    short* __restrict__ fc1_wT, short* __restrict__ fc2_wT)
{
    const int t = threadIdx.x;
    int bid = blockIdx.x;
    if (bid < 8192) { ln_row(x, n1g, n1b, ln_out, bid, t); return; }
    bid -= 8192;
    const int tx = t & 31, ty = t >> 5;
    if (bid < 1728) {
        tc_tile(qkv_w, qkv_wT, 768, 2304, (bid % 72) * 32, (bid / 72) * 32, tx, ty);
    } else if (bid < 2304) {
        bid -= 1728;
        tc_tile(proj_w, proj_wT, 768, 768, (bid % 24) * 32, (bid / 24) * 32, tx, ty);
    } else if (bid < 4608) {
        bid -= 2304;
        tc_tile(fc1_w, fc1_wT, 768, 3072, (bid % 96) * 32, (bid / 96) * 32, tx, ty);
    } else {
        bid -= 4608;
        tc_tile(fc2_w, fc2_wT, 3072, 768, (bid % 24) * 32, (bid / 24) * 32, tx, ty);
    }
}

// ---------------- LayerNorm (standalone, for LN2)
__global__ __launch_bounds__(256) void layernorm_kernel(
    const float* __restrict__ x, const float* __restrict__ g,
    const float* __restrict__ b, short* __restrict__ out)
{
    ln_row(x, g, b, out, blockIdx.x, threadIdx.x);
}

// ---------------- GEMM (single-buffered, BN=128): BK=64, XOR-swizzled LDS,
// XCD-affine flat grid, incremental source pointers.
// MODE 2: out bf16 = gelu_tanh(acc + bias)
// MODE 3: QKV: cols<1536 -> bf16 out; cols>=1536 (V) -> vtout[bh*64+d][n] s16x4
template <int MODE>
__global__ __launch_bounds__(256) void gemm_bt(
    const short* __restrict__ A, const short* __restrict__ Bt,
    const float* __restrict__ bias, const float* __restrict__ res,
    void* __restrict__ out, short* __restrict__ vtout, int M, int N, int K)
{
    __shared__ __align__(16) short As[128 * 64];
    __shared__ __align__(16) short Bs[128 * 64];

    const int t = threadIdx.x;
    const int l = t & 63;
    const int w = t >> 6;
    const int wr = (w >> 1) * 64;
    const int wc = (w & 1) * 64;

    const int ncol = N >> 7;
    const int xcd = blockIdx.x & 7;
    const int idx = blockIdx.x >> 3;
    const int tn = (idx % ncol) << 7;
    const int tm = ((idx / ncol) * 8 + xcd) << 7;

    const int srow = l >> 3;                  // 0..7 within chunk
    const int scol = ((l & 7) ^ srow) * 8;    // pre-swizzled col (shorts)
    const short* aP[4]; const short* bP[4];
#pragma unroll
    for (int c = 0; c < 4; c++) {
        aP[c] = A  + (size_t)(tm + (w * 4 + c) * 8 + srow) * K + scol;
        bP[c] = Bt + (size_t)(tn + (w * 4 + c) * 8 + srow) * K + scol;
    }

    const int fr = l & 15;
    const int g = l >> 4;
    const int sl = fr & 7;            // row component of the XOR swizzle

    f32x4 acc[4][4] = {};

    for (int k0 = 0; k0 < K; k0 += 64) {
#pragma unroll
        for (int c = 0; c < 4; c++) {
            gload16(aP[c], &As[(w * 4 + c) * 512]); aP[c] += 64;
            gload16(bP[c], &Bs[(w * 4 + c) * 512]); bP[c] += 64;
        }
        __syncthreads();

        s16x8 af[4][2], bf[4][2];
#pragma unroll
        for (int m = 0; m < 4; m++) {
            const int rbase = (wr + m * 16 + fr) * 64;
            af[m][0] = *(const s16x8*)&As[rbase + ((g ^ sl) * 8)];
            af[m][1] = *(const s16x8*)&As[rbase + (((4 + g) ^ sl) * 8)];
        }
#pragma unroll
        for (int n = 0; n < 4; n++) {
            const int rbase = (wc + n * 16 + fr) * 64;
            bf[n][0] = *(const s16x8*)&Bs[rbase + ((g ^ sl) * 8)];
            bf[n][1] = *(const s16x8*)&Bs[rbase + (((4 + g) ^ sl) * 8)];
        }
#pragma unroll
        for (int m = 0; m < 4; m++)
#pragma unroll
            for (int n = 0; n < 4; n++) {
                acc[m][n] = __builtin_amdgcn_mfma_f32_16x16x32_bf16(af[m][0], bf[n][0], acc[m][n], 0, 0, 0);
                acc[m][n] = __builtin_amdgcn_mfma_f32_16x16x32_bf16(af[m][1], bf[n][1], acc[m][n], 0, 0, 0);
            }
        __syncthreads();
    }

    const int fq = (l >> 4) * 4;
#pragma unroll
    for (int m = 0; m < 4; m++) {
#pragma unroll
        for (int n = 0; n < 4; n++) {
            const int col = tn + wc + n * 16 + fr;
            const float bv = bias[col];
            if (MODE == 3 && col >= 1536) {
                const int row0 = tm + wr + m * 16 + fq;
                const int bb = row0 >> 10;
                const int nseq = row0 & 1023;
                s16x4 ov;
#pragma unroll
                for (int j = 0; j < 4; j++) ov[j] = f2bf(acc[m][n][j] + bv);
                *(s16x4*)(vtout + (((size_t)(bb * 768 + (col - 1536))) << 10) + nseq) = ov;
            } else {
#pragma unroll
                for (int j = 0; j < 4; j++) {
                    const int row = tm + wr + m * 16 + fq + j;
                    float v = acc[m][n][j] + bv;
                    if (MODE == 2) {
                        const float u = v * (0.7978845608f + 0.0356774081f * v * v);
                        const float e = __builtin_amdgcn_exp2f(u * 2.8853900817779268f);
                        v = v - v * __builtin_amdgcn_rcpf(e + 1.0f);
                    }
                    ((short*)out)[(size_t)row * N + col] = f2bf(v);
                }
            }
        }
    }
}

// ---------------- GEMM db BN=64 (MODE 1): out f32 = acc + bias + res.
#define G_STAGE(AS, BS)                                                     \
    {                                                                       \
        _Pragma("unroll") for (int c = 0; c < 4; c++) {                     \
            gload16(aP[c], &AS[(w * 4 + c) * 512]); aP[c] += 64;            \
        }                                                                   \
        _Pragma("unroll") for (int c = 0; c < 2; c++) {                     \
            gload16(bP[c], &BS[(w * 2 + c) * 512]); bP[c] += 64;            \
        }                                                                   \
    }

#define G_COMPUTE(AS, BS)                                                   \
    {                                                                       \
        s16x8 gaf[4][2], gbf[2][2];                                         \
        _Pragma("unroll") for (int m = 0; m < 4; m++) {                     \
            const int rbase = (wr + m * 16 + fr) * 64;                      \
            gaf[m][0] = *(const s16x8*)&AS[rbase + ((g ^ sl) * 8)];         \
            gaf[m][1] = *(const s16x8*)&AS[rbase + (((4 + g) ^ sl) * 8)];   \
        }                                                                   \
        _Pragma("unroll") for (int n = 0; n < 2; n++) {                     \
            const int rbase = (wc + n * 16 + fr) * 64;                      \
            gbf[n][0] = *(const s16x8*)&BS[rbase + ((g ^ sl) * 8)];         \
            gbf[n][1] = *(const s16x8*)&BS[rbase + (((4 + g) ^ sl) * 8)];   \
        }                                                                   \
        _Pragma("unroll") for (int m = 0; m < 4; m++)                       \
            _Pragma("unroll") for (int n = 0; n < 2; n++) {                 \
                acc[m][n] = __builtin_amdgcn_mfma_f32_16x16x32_bf16(gaf[m][0], gbf[n][0], acc[m][n], 0, 0, 0); \
                acc[m][n] = __builtin_amdgcn_mfma_f32_16x16x32_bf16(gaf[m][1], gbf[n][1], acc[m][n], 0, 0, 0); \
            }                                                               \
    }

__global__ __launch_bounds__(256) void gemm_bt_db(
    const short* __restrict__ A, const short* __restrict__ Bt,
    const float* __restrict__ bias, const float* __restrict__ res,
    float* __restrict__ out, int M, int N, int K)
{
    __shared__ __align__(16) short As0[128 * 64];
    __shared__ __align__(16) short As1[128 * 64];
    __shared__ __align__(16) short Bs0[64 * 64];
    __shared__ __align__(16) short Bs1[64 * 64];

    const int t = threadIdx.x;
    const int l = t & 63;
    const int w = t >> 6;
    const int wr = (w >> 1) * 64;
    const int wc = (w & 1) * 32;

    const int ncol = N >> 6;
    const int xcd = blockIdx.x & 7;
    const int idx = blockIdx.x >> 3;
    const int tn = (idx % ncol) << 6;
    const int tm = ((idx / ncol) * 8 + xcd) << 7;

    const int srow = l >> 3;
    const int scol = ((l & 7) ^ srow) * 8;
    const short* aP[4]; const short* bP[2];
#pragma unroll
    for (int c = 0; c < 4; c++)
        aP[c] = A  + (size_t)(tm + (w * 4 + c) * 8 + srow) * K + scol;
#pragma unroll
    for (int c = 0; c < 2; c++)
        bP[c] = Bt + (size_t)(tn + (w * 2 + c) * 8 + srow) * K + scol;

    const int fr = l & 15;
    const int g = l >> 4;
    const int sl = fr & 7;

    f32x4 acc[4][2] = {};

    G_STAGE(As0, Bs0);
    __syncthreads();

    const int half = K >> 7;
    for (int it = 0; it < half; ++it) {
        G_STAGE(As1, Bs1);
        G_COMPUTE(As0, Bs0);
        __syncthreads();
        if (it < half - 1) G_STAGE(As0, Bs0);
        G_COMPUTE(As1, Bs1);
        __syncthreads();
    }

    const int fq = g * 4;
#pragma unroll
    for (int m = 0; m < 4; m++) {
#pragma unroll
        for (int n = 0; n < 2; n++) {
            const int col = tn + wc + n * 16 + fr;
            const float bv = bias[col];
#pragma unroll
            for (int j = 0; j < 4; j++) {
                const int row = tm + wr + m * 16 + fq + j;
                out[(size_t)row * N + col] = acc[m][n][j] + bv + res[(size_t)row * N + col];
            }
        }
    }
}

// ---------------- Flash attention v8: v7 + setprio(1) around MFMA clusters
#define ATTN_STAGE(KS, VS)                                                  \
    {                                                                       \
        gload16(kP,                    &KS[w * 1024]);                      \
        gload16(kP + (size_t)8 * 2304, &KS[w * 1024 + 512]);                \
        gload16(vP,                    &VS[w * 1024]);                      \
        gload16(vP + (size_t)8 * 1024, &VS[w * 1024 + 512]);                \
        kP += (size_t)64 * 2304;                                            \
        vP += 64;                                                           \
    }

#define ATTN_COMPUTE(KS, VS)                                                \
    {                                                                       \
        s16x8 ka[4][2];                                                     \
        _Pragma("unroll") for (int n = 0; n < 4; n++) {                     \
            const int rbase = (n * 16 + lq) * 64;                           \
            ka[n][0] = *(const s16x8*)&KS[rbase + ((g * 8) ^ swz)];         \
            ka[n][1] = *(const s16x8*)&KS[rbase + ((32 + g * 8) ^ swz)];    \
        }                                                                   \
        f32x4 s[2][4];                                                      \
        __builtin_amdgcn_s_setprio(1);                                      \
        _Pragma("unroll") for (int r = 0; r < 2; r++)                       \
            _Pragma("unroll") for (int n = 0; n < 4; n++) {                 \
                f32x4 sv = {};                                              \
                sv = __builtin_amdgcn_mfma_f32_16x16x32_bf16(ka[n][0], qb[r][0], sv, 0, 0, 0); \
                sv = __builtin_amdgcn_mfma_f32_16x16x32_bf16(ka[n][1], qb[r][1], sv, 0, 0, 0); \
                s[r][n] = sv;                                               \
            }                                                               \
        __builtin_amdgcn_s_setprio(0);                                      \
        s16x8 va[4][2];                                                     \
        _Pragma("unroll") for (int dt = 0; dt < 4; dt++) {                  \
            const int rbase = (dt * 16 + lq) * 64;                          \
            va[dt][0] = *(const s16x8*)&VS[rbase + ((g * 8) ^ swz)];        \
            va[dt][1] = *(const s16x8*)&VS[rbase + ((32 + g * 8) ^ swz)];   \
        }                                                                   \
        _Pragma("unroll") for (int r = 0; r < 2; r++) {                     \
            float mx = fmaxf(fmaxf(s[r][0][0], s[r][0][1]), fmaxf(s[r][0][2], s[r][0][3])); \
            _Pragma("unroll") for (int n = 1; n < 4; n++)                   \
                mx = fmaxf(mx, fmaxf(fmaxf(s[r][n][0], s[r][n][1]), fmaxf(s[r][n][2], s[r][n][3]))); \
            const float mxs = mx * kSc;                                     \
            if (!__all(mxs - m_run[r] <= 8.0f)) {                           \
                float gm = mxs;                                             \
                gm = fmaxf(gm, __shfl_xor(gm, 16, 64));                     \
                gm = fmaxf(gm, __shfl_xor(gm, 32, 64));                     \
                const float mnew = fmaxf(m_run[r], gm);                     \
                const float alpha = __builtin_amdgcn_exp2f(m_run[r] - mnew);\
                m_run[r] = mnew;                                            \
                l_run[r] *= alpha;                                          \
                _Pragma("unroll") for (int dt = 0; dt < 4; dt++) {          \
                    acc[r][dt][0] *= alpha; acc[r][dt][1] *= alpha;         \
                    acc[r][dt][2] *= alpha; acc[r][dt][3] *= alpha;         \
                }                                                           \
            }                                                               \
            const float mb = m_run[r];                                      \
            float ssum = 0.f;                                               \
            _Pragma("unroll") for (int n = 0; n < 4; n++) {                 \
                const float p0 = __builtin_amdgcn_exp2f(s[r][n][0] * kSc - mb); \
                const float p1 = __builtin_amdgcn_exp2f(s[r][n][1] * kSc - mb); \
                const float p2 = __builtin_amdgcn_exp2f(s[r][n][2] * kSc - mb); \
                const float p3 = __builtin_amdgcn_exp2f(s[r][n][3] * kSc - mb); \
                ssum += (p0 + p1) + (p2 + p3);                              \
                unsigned lo, hi;                                            \
                asm("v_cvt_pk_bf16_f32 %0, %1, %2" : "=v"(lo) : "v"(p0), "v"(p1)); \
                asm("v_cvt_pk_bf16_f32 %0, %1, %2" : "=v"(hi) : "v"(p2), "v"(p3)); \
                unsigned* pp = (unsigned*)&Ps[w][r * 16 + lq][n * 16 + g * 4]; \
                pp[0] = lo; pp[1] = hi;                                     \
            }                                                               \
            l_run[r] += ssum;                                               \
        }                                                                   \
        __builtin_amdgcn_s_setprio(1);                                      \
        _Pragma("unroll") for (int r = 0; r < 2; r++) {                     \
            const s16x8 pb0 = *(const s16x8*)&Ps[w][r * 16 + lq][g * 8];    \
            const s16x8 pb1 = *(const s16x8*)&Ps[w][r * 16 + lq][32 + g * 8]; \
            _Pragma("unroll") for (int dt = 0; dt < 4; dt++) {              \
                acc[r][dt] = __builtin_amdgcn_mfma_f32_16x16x32_bf16(va[dt][0], pb0, acc[r][dt], 0, 0, 0); \
                acc[r][dt] = __builtin_amdgcn_mfma_f32_16x16x32_bf16(va[dt][1], pb1, acc[r][dt], 0, 0, 0); \
            }                                                               \
        }                                                                   \
        __builtin_amdgcn_s_setprio(0);                                      \
    }

__global__ __launch_bounds__(256) void attn_kernel(
    const short* __restrict__ qkv, const short* __restrict__ vTg,
    short* __restrict__ out)
{
    const int bid = blockIdx.x;
    const int x = bid & 7;
    const int i = bid >> 3;            // 0..95
    const int bh = x + 8 * (i % 12);   // 0..95
    const int qt = i / 12;             // 0..7
    const int b = bh / 12, h = bh % 12;

    __shared__ __align__(16) short Ks0[64 * 64];
    __shared__ __align__(16) short Ks1[64 * 64];
    __shared__ __align__(16) short Vs0[64 * 64];
    __shared__ __align__(16) short Vs1[64 * 64];
    __shared__ __align__(16) short Ps[4][32][72];

    const int t = threadIdx.x;
    const int l = t & 63;
    const int w = t >> 6;
    const int lq = l & 15;
    const int g = l >> 4;
    const float kSc = 0.18033688011112042f;  // 0.125 * log2(e)

    const int q0 = b * 1024 + qt * 128 + w * 32;

    s16x8 qb[2][2];
#pragma unroll
    for (int r = 0; r < 2; r++) {
        const short* qp = qkv + ((size_t)(q0 + r * 16 + lq)) * 2304 + h * 64 + g * 8;
        qb[r][0] = *(const s16x8*)qp;
        qb[r][1] = *(const s16x8*)(qp + 32);
    }

    const int srow = l >> 3;
    const int scol = ((l & 7) ^ srow) * 8;
    const short* kP = qkv + (size_t)(b * 1024 + w * 16 + srow) * 2304 + 768 + h * 64 + scol;
    const short* vP = vTg + (size_t)(bh * 64 + w * 16 + srow) * 1024 + scol;

    f32x4 acc[2][4] = {};
    float m_run[2] = {-1e30f, -1e30f};
    float l_run[2] = {0.f, 0.f};

    const int swz = (lq & 7) * 8;

    ATTN_STAGE(Ks0, Vs0);
    __syncthreads();

    for (int it = 0; it < 8; ++it) {
        ATTN_STAGE(Ks1, Vs1);
        ATTN_COMPUTE(Ks0, Vs0);
        __syncthreads();
        if (it < 7) ATTN_STAGE(Ks0, Vs0);
        ATTN_COMPUTE(Ks1, Vs1);
        __syncthreads();
    }

#pragma unroll
    for (int r = 0; r < 2; r++) {
        float ls = l_run[r];
        ls += __shfl_xor(ls, 16, 64);
        ls += __shfl_xor(ls, 32, 64);
        const float rinv = 1.0f / ls;
        const int qrow = q0 + r * 16 + lq;
#pragma unroll
        for (int dt = 0; dt < 4; dt++) {
            s16x4 ov;
#pragma unroll
            for (int j = 0; j < 4; j++) ov[j] = f2bf(acc[r][dt][j] * rinv);
            *(s16x4*)(out + (size_t)qrow * 768 + h * 64 + dt * 16 + g * 4) = ov;
        }
    }
}

extern "C" void kernel_launch(void* const* d_in, const int* in_sizes, int n_in,
                              void* d_out, int out_size, void* d_ws, size_t ws_size,
                              hipStream_t stream) {
    const float* x      = (const float*)d_in[0];
    const float* n1g    = (const float*)d_in[1];
    const float* n1b    = (const float*)d_in[2];
    const float* qkv_w  = (const float*)d_in[3];
    const float* qkv_b  = (const float*)d_in[4];
    const float* proj_w = (const float*)d_in[5];
    const float* proj_b = (const float*)d_in[6];
    const float* n2g    = (const float*)d_in[7];
    const float* n2b    = (const float*)d_in[8];
    const float* fc1_w  = (const float*)d_in[9];
    const float* fc1_b  = (const float*)d_in[10];
    const float* fc2_w  = (const float*)d_in[11];
    const float* fc2_b  = (const float*)d_in[12];
    float* out = (float*)d_out;

    char* ws = (char*)d_ws;
    short* qkv_wT  = (short*)(ws + 0);           // [2304][768] bf16
    short* proj_wT = (short*)(ws + 3538944);     // [768][768]
    short* fc1_wT  = (short*)(ws + 4718592);     // [3072][768]
    short* fc2_wT  = (short*)(ws + 9437184);     // [768][3072]
    short* bufA    = (short*)(ws + 14155776);    // 8192x768 bf16 (ln1/attn_out/ln2)
    short* bufB    = (short*)(ws + 26738688);    // 8192x3072 bf16 (qkv / h1)
    short* vT      = (short*)(ws + 64487424);    // 96x64x1024 bf16
    float* bufC    = (float*)(ws + 77070336);    // 8192x768 f32 (x1)

    prep_all<<<8192 + 6912, 256, 0, stream>>>(
        x, n1g, n1b, bufA,
        qkv_w, proj_w, fc1_w, fc2_w, qkv_wT, proj_wT, fc1_wT, fc2_wT);

    gemm_bt<3><<<64 * (2304 / 128), 256, 0, stream>>>(
        bufA, qkv_wT, qkv_b, nullptr, bufB, vT, 8192, 2304, 768);

    attn_kernel<<<768, 256, 0, stream>>>(bufB, vT, bufA);

    gemm_bt_db<<<64 * (768 / 64), 256, 0, stream>>>(
        bufA, proj_wT, proj_b, x, bufC, 8192, 768, 768);

    layernorm_kernel<<<8192, 256, 0, stream>>>(bufC, n2g, n2b, bufA);

    gemm_bt<2><<<64 * (3072 / 128), 256, 0, stream>>>(
        bufA, fc1_wT, fc1_b, nullptr, bufB, nullptr, 8192, 3072, 768);

    gemm_bt_db<<<64 * (768 / 64), 256, 0, stream>>>(
        bufB, fc2_wT, fc2_b, bufC, out, 8192, 768, 3072);
}

// Round 19
// 235.121 us; speedup vs baseline: 1.0189x; 1.0189x over previous
//
#include <hip/hip_runtime.h>

typedef __attribute__((ext_vector_type(8))) short s16x8;
typedef __attribute__((ext_vector_type(4))) short s16x4;
typedef __attribute__((ext_vector_type(4))) float f32x4;

static __device__ __forceinline__ short f2bf(float f) {
    unsigned u = __builtin_bit_cast(unsigned, f);
    u = (u + 0x7FFFu + ((u >> 16) & 1u)) >> 16;
    return (short)u;
}

__device__ __forceinline__ void gload16(const short* g, short* l) {
    __builtin_amdgcn_global_load_lds(
        (const __attribute__((address_space(1))) void*)g,
        (__attribute__((address_space(3))) void*)l,
        16, 0, 0);
}

// ---------------- prep: LN1 rows + all 4 weight transposes in ONE launch
__device__ __forceinline__ void tc_tile(
    const float* __restrict__ W, short* __restrict__ Wt, int K, int N,
    int bx, int by, int tx, int ty)
{
    __shared__ float tile[32][33];
    for (int i = 0; i < 32; i += 8)
        tile[ty + i][tx] = W[(size_t)(by + ty + i) * N + bx + tx];
    __syncthreads();
    for (int i = 0; i < 32; i += 8)
        Wt[(size_t)(bx + ty + i) * K + by + tx] = f2bf(tile[tx][ty + i]);
}

__device__ __forceinline__ void ln_row(
    const float* __restrict__ x, const float* __restrict__ g,
    const float* __restrict__ b, short* __restrict__ out, int row, int t)
{
    __shared__ float red[4];
    const float* xr = x + (size_t)row * 768;
    float v0 = xr[t], v1 = xr[t + 256], v2 = xr[t + 512];
    float s = v0 + v1 + v2;
    for (int off = 32; off >= 1; off >>= 1) s += __shfl_down(s, off, 64);
    if ((t & 63) == 0) red[t >> 6] = s;
    __syncthreads();
    const float mean = (red[0] + red[1] + red[2] + red[3]) * (1.0f / 768.0f);
    const float d0 = v0 - mean, d1 = v1 - mean, d2 = v2 - mean;
    __syncthreads();
    float ss = d0 * d0 + d1 * d1 + d2 * d2;
    for (int off = 32; off >= 1; off >>= 1) ss += __shfl_down(ss, off, 64);
    if ((t & 63) == 0) red[t >> 6] = ss;
    __syncthreads();
    const float var = (red[0] + red[1] + red[2] + red[3]) * (1.0f / 768.0f);
    const float rstd = rsqrtf(var + 1e-5f);
    out[(size_t)row * 768 + t]       = f2bf(d0 * rstd * g[t] + b[t]);
    out[(size_t)row * 768 + t + 256] = f2bf(d1 * rstd * g[t + 256] + b[t + 256]);
    out[(size_t)row * 768 + t + 512] = f2bf(d2 * rstd * g[t + 512] + b[t + 512]);
}

// blocks: 0..8191 LN1 | then qkv 1728 | proj 576 | fc1 2304 | fc2 2304
__global__ __launch_bounds__(256) void prep_all(
    const float* __restrict__ x, const float* __restrict__ n1g,
    const float* __restrict__ n1b, short* __restrict__ ln_out,
    const float* __restrict__ qkv_w, const float* __restrict__ proj_w,
    const float* __restrict__ fc1_w, const float* __restrict__ fc2_w,
    short* __restrict__ qkv_wT, short* __restrict__ proj_wT,
    short* __restrict__ fc1_wT, short* __restrict__ fc2_wT)
{
    const int t = threadIdx.x;
    int bid = blockIdx.x;
    if (bid < 8192) { ln_row(x, n1g, n1b, ln_out, bid, t); return; }
    bid -= 8192;
    const int tx = t & 31, ty = t >> 5;
    if (bid < 1728) {
        tc_tile(qkv_w, qkv_wT, 768, 2304, (bid % 72) * 32, (bid / 72) * 32, tx, ty);
    } else if (bid < 2304) {
        bid -= 1728;
        tc_tile(proj_w, proj_wT, 768, 768, (bid % 24) * 32, (bid / 24) * 32, tx, ty);
    } else if (bid < 4608) {
        bid -= 2304;
        tc_tile(fc1_w, fc1_wT, 768, 3072, (bid % 96) * 32, (bid / 96) * 32, tx, ty);
    } else {
        bid -= 4608;
        tc_tile(fc2_w, fc2_wT, 3072, 768, (bid % 24) * 32, (bid / 24) * 32, tx, ty);
    }
}

// ---------------- LayerNorm (standalone, for LN2)
__global__ __launch_bounds__(256) void layernorm_kernel(
    const float* __restrict__ x, const float* __restrict__ g,
    const float* __restrict__ b, short* __restrict__ out)
{
    ln_row(x, g, b, out, blockIdx.x, threadIdx.x);
}

// ---------------- GEMM (single-buffered, BN=128): BK=64, XOR-swizzled LDS,
// XCD-affine flat grid.  (exact round-17 body — k0-offset addressing)
// MODE 2: out bf16 = gelu_tanh(acc + bias)
// MODE 3: QKV: cols<1536 -> bf16 out; cols>=1536 (V) -> vtout[bh*64+d][n] s16x4
template <int MODE>
__global__ __launch_bounds__(256) void gemm_bt(
    const short* __restrict__ A, const short* __restrict__ Bt,
    const float* __restrict__ bias, const float* __restrict__ res,
    void* __restrict__ out, short* __restrict__ vtout, int M, int N, int K)
{
    __shared__ __align__(16) short As[128 * 64];
    __shared__ __align__(16) short Bs[128 * 64];

    const int t = threadIdx.x;
    const int l = t & 63;
    const int w = t >> 6;
    const int wr = (w >> 1) * 64;
    const int wc = (w & 1) * 64;

    const int ncol = N >> 7;
    const int xcd = blockIdx.x & 7;
    const int idx = blockIdx.x >> 3;
    const int tn = (idx % ncol) << 7;
    const int tm = ((idx / ncol) * 8 + xcd) << 7;

    const int srow = l >> 3;                  // 0..7 within chunk
    const int scol = ((l & 7) ^ srow) * 8;    // pre-swizzled col (shorts)
    const short* aS[4]; const short* bS[4];
#pragma unroll
    for (int c = 0; c < 4; c++) {
        aS[c] = A  + (size_t)(tm + (w * 4 + c) * 8 + srow) * K + scol;
        bS[c] = Bt + (size_t)(tn + (w * 4 + c) * 8 + srow) * K + scol;
    }

    const int fr = l & 15;
    const int g = l >> 4;
    const int sl = fr & 7;            // row component of the XOR swizzle

    f32x4 acc[4][4] = {};

    for (int k0 = 0; k0 < K; k0 += 64) {
#pragma unroll
        for (int c = 0; c < 4; c++) {
            gload16(aS[c] + k0, &As[(w * 4 + c) * 512]);
            gload16(bS[c] + k0, &Bs[(w * 4 + c) * 512]);
        }
        __syncthreads();

        s16x8 af[4][2], bf[4][2];
#pragma unroll
        for (int m = 0; m < 4; m++) {
            const int rbase = (wr + m * 16 + fr) * 64;
            af[m][0] = *(const s16x8*)&As[rbase + ((g ^ sl) * 8)];
            af[m][1] = *(const s16x8*)&As[rbase + (((4 + g) ^ sl) * 8)];
        }
#pragma unroll
        for (int n = 0; n < 4; n++) {
            const int rbase = (wc + n * 16 + fr) * 64;
            bf[n][0] = *(const s16x8*)&Bs[rbase + ((g ^ sl) * 8)];
            bf[n][1] = *(const s16x8*)&Bs[rbase + (((4 + g) ^ sl) * 8)];
        }
#pragma unroll
        for (int m = 0; m < 4; m++)
#pragma unroll
            for (int n = 0; n < 4; n++) {
                acc[m][n] = __builtin_amdgcn_mfma_f32_16x16x32_bf16(af[m][0], bf[n][0], acc[m][n], 0, 0, 0);
                acc[m][n] = __builtin_amdgcn_mfma_f32_16x16x32_bf16(af[m][1], bf[n][1], acc[m][n], 0, 0, 0);
            }
        __syncthreads();
    }

    const int fq = (l >> 4) * 4;
#pragma unroll
    for (int m = 0; m < 4; m++) {
#pragma unroll
        for (int n = 0; n < 4; n++) {
            const int col = tn + wc + n * 16 + fr;
            const float bv = bias[col];
            if (MODE == 3 && col >= 1536) {
                const int row0 = tm + wr + m * 16 + fq;
                const int bb = row0 >> 10;
                const int nseq = row0 & 1023;
                s16x4 ov;
#pragma unroll
                for (int j = 0; j < 4; j++) ov[j] = f2bf(acc[m][n][j] + bv);
                *(s16x4*)(vtout + (((size_t)(bb * 768 + (col - 1536))) << 10) + nseq) = ov;
            } else {
#pragma unroll
                for (int j = 0; j < 4; j++) {
                    const int row = tm + wr + m * 16 + fq + j;
                    float v = acc[m][n][j] + bv;
                    if (MODE == 2) {
                        const float u = v * (0.7978845608f + 0.0356774081f * v * v);
                        const float e = __builtin_amdgcn_exp2f(u * 2.8853900817779268f);
                        v = v - v * __builtin_amdgcn_rcpf(e + 1.0f);
                    }
                    ((short*)out)[(size_t)row * N + col] = f2bf(v);
                }
            }
        }
    }
}

// ---------------- GEMM db BN=64 (MODE 1): out f32 = acc + bias + res.
#define G_STAGE(AS, BS)                                                     \
    {                                                                       \
        _Pragma("unroll") for (int c = 0; c < 4; c++) {                     \
            gload16(aP[c], &AS[(w * 4 + c) * 512]); aP[c] += 64;            \
        }                                                                   \
        _Pragma("unroll") for (int c = 0; c < 2; c++) {                     \
            gload16(bP[c], &BS[(w * 2 + c) * 512]); bP[c] += 64;            \
        }                                                                   \
    }

#define G_COMPUTE(AS, BS)                                                   \
    {                                                                       \
        s16x8 gaf[4][2], gbf[2][2];                                         \
        _Pragma("unroll") for (int m = 0; m < 4; m++) {                     \
            const int rbase = (wr + m * 16 + fr) * 64;                      \
            gaf[m][0] = *(const s16x8*)&AS[rbase + ((g ^ sl) * 8)];         \
            gaf[m][1] = *(const s16x8*)&AS[rbase + (((4 + g) ^ sl) * 8)];   \
        }                                                                   \
        _Pragma("unroll") for (int n = 0; n < 2; n++) {                     \
            const int rbase = (wc + n * 16 + fr) * 64;                      \
            gbf[n][0] = *(const s16x8*)&BS[rbase + ((g ^ sl) * 8)];         \
            gbf[n][1] = *(const s16x8*)&BS[rbase + (((4 + g) ^ sl) * 8)];   \
        }                                                                   \
        _Pragma("unroll") for (int m = 0; m < 4; m++)                       \
            _Pragma("unroll") for (int n = 0; n < 2; n++) {                 \
                acc[m][n] = __builtin_amdgcn_mfma_f32_16x16x32_bf16(gaf[m][0], gbf[n][0], acc[m][n], 0, 0, 0); \
                acc[m][n] = __builtin_amdgcn_mfma_f32_16x16x32_bf16(gaf[m][1], gbf[n][1], acc[m][n], 0, 0, 0); \
            }                                                               \
    }

__global__ __launch_bounds__(256) void gemm_bt_db(
    const short* __restrict__ A, const short* __restrict__ Bt,
    const float* __restrict__ bias, const float* __restrict__ res,
    float* __restrict__ out, int M, int N, int K)
{
    __shared__ __align__(16) short As0[128 * 64];
    __shared__ __align__(16) short As1[128 * 64];
    __shared__ __align__(16) short Bs0[64 * 64];
    __shared__ __align__(16) short Bs1[64 * 64];

    const int t = threadIdx.x;
    const int l = t & 63;
    const int w = t >> 6;
    const int wr = (w >> 1) * 64;
    const int wc = (w & 1) * 32;

    const int ncol = N >> 6;
    const int xcd = blockIdx.x & 7;
    const int idx = blockIdx.x >> 3;
    const int tn = (idx % ncol) << 6;
    const int tm = ((idx / ncol) * 8 + xcd) << 7;

    const int srow = l >> 3;
    const int scol = ((l & 7) ^ srow) * 8;
    const short* aP[4]; const short* bP[2];
#pragma unroll
    for (int c = 0; c < 4; c++)
        aP[c] = A  + (size_t)(tm + (w * 4 + c) * 8 + srow) * K + scol;
#pragma unroll
    for (int c = 0; c < 2; c++)
        bP[c] = Bt + (size_t)(tn + (w * 2 + c) * 8 + srow) * K + scol;

    const int fr = l & 15;
    const int g = l >> 4;
    const int sl = fr & 7;

    f32x4 acc[4][2] = {};

    G_STAGE(As0, Bs0);
    __syncthreads();

    const int half = K >> 7;
    for (int it = 0; it < half; ++it) {
        G_STAGE(As1, Bs1);
        G_COMPUTE(As0, Bs0);
        __syncthreads();
        if (it < half - 1) G_STAGE(As0, Bs0);
        G_COMPUTE(As1, Bs1);
        __syncthreads();
    }

    const int fq = g * 4;
#pragma unroll
    for (int m = 0; m < 4; m++) {
#pragma unroll
        for (int n = 0; n < 2; n++) {
            const int col = tn + wc + n * 16 + fr;
            const float bv = bias[col];
#pragma unroll
            for (int j = 0; j < 4; j++) {
                const int row = tm + wr + m * 16 + fq + j;
                out[(size_t)row * N + col] = acc[m][n][j] + bv + res[(size_t)row * N + col];
            }
        }
    }
}

// ---------------- Flash attention v8 (setprio around MFMA clusters)
#define ATTN_STAGE(KS, VS)                                                  \
    {                                                                       \
        gload16(kP,                    &KS[w * 1024]);                      \
        gload16(kP + (size_t)8 * 2304, &KS[w * 1024 + 512]);                \
        gload16(vP,                    &VS[w * 1024]);                      \
        gload16(vP + (size_t)8 * 1024, &VS[w * 1024 + 512]);                \
        kP += (size_t)64 * 2304;                                            \
        vP += 64;                                                           \
    }

#define ATTN_COMPUTE(KS, VS)                                                \
    {                                                                       \
        s16x8 ka[4][2];                                                     \
        _Pragma("unroll") for (int n = 0; n < 4; n++) {                     \
            const int rbase = (n * 16 + lq) * 64;                           \
            ka[n][0] = *(const s16x8*)&KS[rbase + ((g * 8) ^ swz)];         \
            ka[n][1] = *(const s16x8*)&KS[rbase + ((32 + g * 8) ^ swz)];    \
        }                                                                   \
        f32x4 s[2][4];                                                      \
        __builtin_amdgcn_s_setprio(1);                                      \
        _Pragma("unroll") for (int r = 0; r < 2; r++)                       \
            _Pragma("unroll") for (int n = 0; n < 4; n++) {                 \
                f32x4 sv = {};                                              \
                sv = __builtin_amdgcn_mfma_f32_16x16x32_bf16(ka[n][0], qb[r][0], sv, 0, 0, 0); \
                sv = __builtin_amdgcn_mfma_f32_16x16x32_bf16(ka[n][1], qb[r][1], sv, 0, 0, 0); \
                s[r][n] = sv;                                               \
            }                                                               \
        __builtin_amdgcn_s_setprio(0);                                      \
        s16x8 va[4][2];                                                     \
        _Pragma("unroll") for (int dt = 0; dt < 4; dt++) {                  \
            const int rbase = (dt * 16 + lq) * 64;                          \
            va[dt][0] = *(const s16x8*)&VS[rbase + ((g * 8) ^ swz)];        \
            va[dt][1] = *(const s16x8*)&VS[rbase + ((32 + g * 8) ^ swz)];   \
        }                                                                   \
        _Pragma("unroll") for (int r = 0; r < 2; r++) {                     \
            float mx = fmaxf(fmaxf(s[r][0][0], s[r][0][1]), fmaxf(s[r][0][2], s[r][0][3])); \
            _Pragma("unroll") for (int n = 1; n < 4; n++)                   \
                mx = fmaxf(mx, fmaxf(fmaxf(s[r][n][0], s[r][n][1]), fmaxf(s[r][n][2], s[r][n][3]))); \
            const float mxs = mx * kSc;                                     \
            if (!__all(mxs - m_run[r] <= 8.0f)) {                           \
                float gm = mxs;                                             \
                gm = fmaxf(gm, __shfl_xor(gm, 16, 64));                     \
                gm = fmaxf(gm, __shfl_xor(gm, 32, 64));                     \
                const float mnew = fmaxf(m_run[r], gm);                     \
                const float alpha = __builtin_amdgcn_exp2f(m_run[r] - mnew);\
                m_run[r] = mnew;                                            \
                l_run[r] *= alpha;                                          \
                _Pragma("unroll") for (int dt = 0; dt < 4; dt++) {          \
                    acc[r][dt][0] *= alpha; acc[r][dt][1] *= alpha;         \
                    acc[r][dt][2] *= alpha; acc[r][dt][3] *= alpha;         \
                }                                                           \
            }                                                               \
            const float mb = m_run[r];                                      \
            float ssum = 0.f;                                               \
            _Pragma("unroll") for (int n = 0; n < 4; n++) {                 \
                const float p0 = __builtin_amdgcn_exp2f(s[r][n][0] * kSc - mb); \
                const float p1 = __builtin_amdgcn_exp2f(s[r][n][1] * kSc - mb); \
                const float p2 = __builtin_amdgcn_exp2f(s[r][n][2] * kSc - mb); \
                const float p3 = __builtin_amdgcn_exp2f(s[r][n][3] * kSc - mb); \
                ssum += (p0 + p1) + (p2 + p3);                              \
                unsigned lo, hi;                                            \
                asm("v_cvt_pk_bf16_f32 %0, %1, %2" : "=v"(lo) : "v"(p0), "v"(p1)); \
                asm("v_cvt_pk_bf16_f32 %0, %1, %2" : "=v"(hi) : "v"(p2), "v"(p3)); \
                unsigned* pp = (unsigned*)&Ps[w][r * 16 + lq][n * 16 + g * 4]; \
                pp[0] = lo; pp[1] = hi;                                     \
            }                                                               \
            l_run[r] += ssum;                                               \
        }                                                                   \
        __builtin_amdgcn_s_setprio(1);                                      \
        _Pragma("unroll") for (int r = 0; r < 2; r++) {                     \
            const s16x8 pb0 = *(const s16x8*)&Ps[w][r * 16 + lq][g * 8];    \
            const s16x8 pb1 = *(const s16x8*)&Ps[w][r * 16 + lq][32 + g * 8]; \
            _Pragma("unroll") for (int dt = 0; dt < 4; dt++) {              \
                acc[r][dt] = __builtin_amdgcn_mfma_f32_16x16x32_bf16(va[dt][0], pb0, acc[r][dt], 0, 0, 0); \
                acc[r][dt] = __builtin_amdgcn_mfma_f32_16x16x32_bf16(va[dt][1], pb1, acc[r][dt], 0, 0, 0); \
            }                                                               \
        }                                                                   \
        __builtin_amdgcn_s_setprio(0);                                      \
    }

__global__ __launch_bounds__(256) void attn_kernel(
    const short* __restrict__ qkv, const short* __restrict__ vTg,
    short* __restrict__ out)
{
    const int bid = blockIdx.x;
    const int x = bid & 7;
    const int i = bid >> 3;            // 0..95
    const int bh = x + 8 * (i % 12);   // 0..95
    const int qt = i / 12;             // 0..7
    const int b = bh / 12, h = bh % 12;

    __shared__ __align__(16) short Ks0[64 * 64];
    __shared__ __align__(16) short Ks1[64 * 64];
    __shared__ __align__(16) short Vs0[64 * 64];
    __shared__ __align__(16) short Vs1[64 * 64];
    __shared__ __align__(16) short Ps[4][32][72];

    const int t = threadIdx.x;
    const int l = t & 63;
    const int w = t >> 6;
    const int lq = l & 15;
    const int g = l >> 4;
    const float kSc = 0.18033688011112042f;  // 0.125 * log2(e)

    const int q0 = b * 1024 + qt * 128 + w * 32;

    s16x8 qb[2][2];
#pragma unroll
    for (int r = 0; r < 2; r++) {
        const short* qp = qkv + ((size_t)(q0 + r * 16 + lq)) * 2304 + h * 64 + g * 8;
        qb[r][0] = *(const s16x8*)qp;
        qb[r][1] = *(const s16x8*)(qp + 32);
    }

    const int srow = l >> 3;
    const int scol = ((l & 7) ^ srow) * 8;
    const short* kP = qkv + (size_t)(b * 1024 + w * 16 + srow) * 2304 + 768 + h * 64 + scol;
    const short* vP = vTg + (size_t)(bh * 64 + w * 16 + srow) * 1024 + scol;

    f32x4 acc[2][4] = {};
    float m_run[2] = {-1e30f, -1e30f};
    float l_run[2] = {0.f, 0.f};

    const int swz = (lq & 7) * 8;

    ATTN_STAGE(Ks0, Vs0);
    __syncthreads();

    for (int it = 0; it < 8; ++it) {
        ATTN_STAGE(Ks1, Vs1);
        ATTN_COMPUTE(Ks0, Vs0);
        __syncthreads();
        if (it < 7) ATTN_STAGE(Ks0, Vs0);
        ATTN_COMPUTE(Ks1, Vs1);
        __syncthreads();
    }

#pragma unroll
    for (int r = 0; r < 2; r++) {
        float ls = l_run[r];
        ls += __shfl_xor(ls, 16, 64);
        ls += __shfl_xor(ls, 32, 64);
        const float rinv = 1.0f / ls;
        const int qrow = q0 + r * 16 + lq;
#pragma unroll
        for (int dt = 0; dt < 4; dt++) {
            s16x4 ov;
#pragma unroll
            for (int j = 0; j < 4; j++) ov[j] = f2bf(acc[r][dt][j] * rinv);
            *(s16x4*)(out + (size_t)qrow * 768 + h * 64 + dt * 16 + g * 4) = ov;
        }
    }
}

extern "C" void kernel_launch(void* const* d_in, const int* in_sizes, int n_in,
                              void* d_out, int out_size, void* d_ws, size_t ws_size,
                              hipStream_t stream) {
    const float* x      = (const float*)d_in[0];
    const float* n1g    = (const float*)d_in[1];
    const float* n1b    = (const float*)d_in[2];
    const float* qkv_w  = (const float*)d_in[3];
    const float* qkv_b  = (const float*)d_in[4];
    const float* proj_w = (const float*)d_in[5];
    const float* proj_b = (const float*)d_in[6];
    const float* n2g    = (const float*)d_in[7];
    const float* n2b    = (const float*)d_in[8];
    const float* fc1_w  = (const float*)d_in[9];
    const float* fc1_b  = (const float*)d_in[10];
    const float* fc2_w  = (const float*)d_in[11];
    const float* fc2_b  = (const float*)d_in[12];
    float* out = (float*)d_out;

    char* ws = (char*)d_ws;
    short* qkv_wT  = (short*)(ws + 0);           // [2304][768] bf16
    short* proj_wT = (short*)(ws + 3538944);     // [768][768]
    short* fc1_wT  = (short*)(ws + 4718592);     // [3072][768]
    short* fc2_wT  = (short*)(ws + 9437184);     // [768][3072]
    short* bufA    = (short*)(ws + 14155776);    // 8192x768 bf16 (ln1/attn_out/ln2)
    short* bufB    = (short*)(ws + 26738688);    // 8192x3072 bf16 (qkv / h1)
    short* vT      = (short*)(ws + 64487424);    // 96x64x1024 bf16
    float* bufC    = (float*)(ws + 77070336);    // 8192x768 f32 (x1)

    prep_all<<<8192 + 6912, 256, 0, stream>>>(
        x, n1g, n1b, bufA,
        qkv_w, proj_w, fc1_w, fc2_w, qkv_wT, proj_wT, fc1_wT, fc2_wT);

    gemm_bt<3><<<64 * (2304 / 128), 256, 0, stream>>>(
        bufA, qkv_wT, qkv_b, nullptr, bufB, vT, 8192, 2304, 768);

    attn_kernel<<<768, 256, 0, stream>>>(bufB, vT, bufA);

    gemm_bt_db<<<64 * (768 / 64), 256, 0, stream>>>(
        bufA, proj_wT, proj_b, x, bufC, 8192, 768, 768);

    layernorm_kernel<<<8192, 256, 0, stream>>>(bufC, n2g, n2b, bufA);

    gemm_bt<2><<<64 * (3072 / 128), 256, 0, stream>>>(
        bufA, fc1_wT, fc1_b, nullptr, bufB, nullptr, 8192, 3072, 768);

    gemm_bt_db<<<64 * (768 / 64), 256, 0, stream>>>(
        bufB, fc2_wT, fc2_b, bufC, out, 8192, 768, 3072);
}

// Round 20
// 231.426 us; speedup vs baseline: 1.0352x; 1.0160x over previous
//
#include <hip/hip_runtime.h>

typedef __attribute__((ext_vector_type(8))) short s16x8;
typedef __attribute__((ext_vector_type(4))) short s16x4;
typedef __attribute__((ext_vector_type(4))) float f32x4;

static __device__ __forceinline__ short f2bf(float f) {
    unsigned u = __builtin_bit_cast(unsigned, f);
    u = (u + 0x7FFFu + ((u >> 16) & 1u)) >> 16;
    return (short)u;
}
static __device__ __forceinline__ float bf2f(short h) {
    unsigned u = ((unsigned)(unsigned short)h) << 16;
    return __builtin_bit_cast(float, u);
}

__device__ __forceinline__ void gload16(const short* g, short* l) {
    __builtin_amdgcn_global_load_lds(
        (const __attribute__((address_space(1))) void*)g,
        (__attribute__((address_space(3))) void*)l,
        16, 0, 0);
}

// ---------------- prep: LN1 rows + all 4 weight transposes in ONE launch
__device__ __forceinline__ void tc_tile(
    const float* __restrict__ W, short* __restrict__ Wt, int K, int N,
    int bx, int by, int tx, int ty)
{
    __shared__ float tile[32][33];
    for (int i = 0; i < 32; i += 8)
        tile[ty + i][tx] = W[(size_t)(by + ty + i) * N + bx + tx];
    __syncthreads();
    for (int i = 0; i < 32; i += 8)
        Wt[(size_t)(bx + ty + i) * K + by + tx] = f2bf(tile[tx][ty + i]);
}

__device__ __forceinline__ void ln_row(
    const float* __restrict__ x, const float* __restrict__ g,
    const float* __restrict__ b, short* __restrict__ out, int row, int t)
{
    __shared__ float red[4];
    const float* xr = x + (size_t)row * 768;
    float v0 = xr[t], v1 = xr[t + 256], v2 = xr[t + 512];
    float s = v0 + v1 + v2;
    for (int off = 32; off >= 1; off >>= 1) s += __shfl_down(s, off, 64);
    if ((t & 63) == 0) red[t >> 6] = s;
    __syncthreads();
    const float mean = (red[0] + red[1] + red[2] + red[3]) * (1.0f / 768.0f);
    const float d0 = v0 - mean, d1 = v1 - mean, d2 = v2 - mean;
    __syncthreads();
    float ss = d0 * d0 + d1 * d1 + d2 * d2;
    for (int off = 32; off >= 1; off >>= 1) ss += __shfl_down(ss, off, 64);
    if ((t & 63) == 0) red[t >> 6] = ss;
    __syncthreads();
    const float var = (red[0] + red[1] + red[2] + red[3]) * (1.0f / 768.0f);
    const float rstd = rsqrtf(var + 1e-5f);
    out[(size_t)row * 768 + t]       = f2bf(d0 * rstd * g[t] + b[t]);
    out[(size_t)row * 768 + t + 256] = f2bf(d1 * rstd * g[t + 256] + b[t + 256]);
    out[(size_t)row * 768 + t + 512] = f2bf(d2 * rstd * g[t + 512] + b[t + 512]);
}

// blocks: 0..8191 LN1 | then qkv 1728 | proj 576 | fc1 2304 | fc2 2304
__global__ __launch_bounds__(256) void prep_all(
    const float* __restrict__ x, const float* __restrict__ n1g,
    const float* __restrict__ n1b, short* __restrict__ ln_out,
    const float* __restrict__ qkv_w, const float* __restrict__ proj_w,
    const float* __restrict__ fc1_w, const float* __restrict__ fc2_w,
    short* __restrict__ qkv_wT, short* __restrict__ proj_wT,
    short* __restrict__ fc1_wT, short* __restrict__ fc2_wT)
{
    const int t = threadIdx.x;
    int bid = blockIdx.x;
    if (bid < 8192) { ln_row(x, n1g, n1b, ln_out, bid, t); return; }
    bid -= 8192;
    const int tx = t & 31, ty = t >> 5;
    if (bid < 1728) {
        tc_tile(qkv_w, qkv_wT, 768, 2304, (bid % 72) * 32, (bid / 72) * 32, tx, ty);
    } else if (bid < 2304) {
        bid -= 1728;
        tc_tile(proj_w, proj_wT, 768, 768, (bid % 24) * 32, (bid / 24) * 32, tx, ty);
    } else if (bid < 4608) {
        bid -= 2304;
        tc_tile(fc1_w, fc1_wT, 768, 3072, (bid % 96) * 32, (bid / 96) * 32, tx, ty);
    } else {
        bid -= 4608;
        tc_tile(fc2_w, fc2_wT, 3072, 768, (bid % 24) * 32, (bid / 24) * 32, tx, ty);
    }
}

// ---------------- LayerNorm over bf16 trunk (LN2): 192 threads, ushort4 loads
__global__ __launch_bounds__(192) void layernorm_bf16(
    const short* __restrict__ x, const float* __restrict__ g,
    const float* __restrict__ b, short* __restrict__ out)
{
    __shared__ float red[3];
    const int row = blockIdx.x;
    const int t = threadIdx.x;           // 0..191, covers 4 elems each
    const s16x4 v = *(const s16x4*)(x + (size_t)row * 768 + t * 4);
    float f0 = bf2f(v[0]), f1 = bf2f(v[1]), f2 = bf2f(v[2]), f3 = bf2f(v[3]);

    float s = (f0 + f1) + (f2 + f3);
    for (int off = 32; off >= 1; off >>= 1) s += __shfl_down(s, off, 64);
    if ((t & 63) == 0) red[t >> 6] = s;
    __syncthreads();
    const float mean = (red[0] + red[1] + red[2]) * (1.0f / 768.0f);
    const float d0 = f0 - mean, d1 = f1 - mean, d2 = f2 - mean, d3 = f3 - mean;
    __syncthreads();
    float ss = (d0 * d0 + d1 * d1) + (d2 * d2 + d3 * d3);
    for (int off = 32; off >= 1; off >>= 1) ss += __shfl_down(ss, off, 64);
    if ((t & 63) == 0) red[t >> 6] = ss;
    __syncthreads();
    const float var = (red[0] + red[1] + red[2]) * (1.0f / 768.0f);
    const float rstd = rsqrtf(var + 1e-5f);
    s16x4 o;
    o[0] = f2bf(d0 * rstd * g[t * 4 + 0] + b[t * 4 + 0]);
    o[1] = f2bf(d1 * rstd * g[t * 4 + 1] + b[t * 4 + 1]);
    o[2] = f2bf(d2 * rstd * g[t * 4 + 2] + b[t * 4 + 2]);
    o[3] = f2bf(d3 * rstd * g[t * 4 + 3] + b[t * 4 + 3]);
    *(s16x4*)(out + (size_t)row * 768 + t * 4) = o;
}

// ---------------- GEMM (single-buffered, BN=128): BK=64, XOR-swizzled LDS,
// XCD-affine flat grid.  (round-17/19 body)
// MODE 2: out bf16 = gelu_tanh(acc + bias)
// MODE 3: QKV: cols<1536 -> bf16 out; cols>=1536 (V) -> vtout[bh*64+d][n] s16x4
template <int MODE>
__global__ __launch_bounds__(256) void gemm_bt(
    const short* __restrict__ A, const short* __restrict__ Bt,
    const float* __restrict__ bias, const float* __restrict__ res,
    void* __restrict__ out, short* __restrict__ vtout, int M, int N, int K)
{
    __shared__ __align__(16) short As[128 * 64];
    __shared__ __align__(16) short Bs[128 * 64];

    const int t = threadIdx.x;
    const int l = t & 63;
    const int w = t >> 6;
    const int wr = (w >> 1) * 64;
    const int wc = (w & 1) * 64;

    const int ncol = N >> 7;
    const int xcd = blockIdx.x & 7;
    const int idx = blockIdx.x >> 3;
    const int tn = (idx % ncol) << 7;
    const int tm = ((idx / ncol) * 8 + xcd) << 7;

    const int srow = l >> 3;                  // 0..7 within chunk
    const int scol = ((l & 7) ^ srow) * 8;    // pre-swizzled col (shorts)
    const short* aS[4]; const short* bS[4];
#pragma unroll
    for (int c = 0; c < 4; c++) {
        aS[c] = A  + (size_t)(tm + (w * 4 + c) * 8 + srow) * K + scol;
        bS[c] = Bt + (size_t)(tn + (w * 4 + c) * 8 + srow) * K + scol;
    }

    const int fr = l & 15;
    const int g = l >> 4;
    const int sl = fr & 7;            // row component of the XOR swizzle

    f32x4 acc[4][4] = {};

    for (int k0 = 0; k0 < K; k0 += 64) {
#pragma unroll
        for (int c = 0; c < 4; c++) {
            gload16(aS[c] + k0, &As[(w * 4 + c) * 512]);
            gload16(bS[c] + k0, &Bs[(w * 4 + c) * 512]);
        }
        __syncthreads();

        s16x8 af[4][2], bf[4][2];
#pragma unroll
        for (int m = 0; m < 4; m++) {
            const int rbase = (wr + m * 16 + fr) * 64;
            af[m][0] = *(const s16x8*)&As[rbase + ((g ^ sl) * 8)];
            af[m][1] = *(const s16x8*)&As[rbase + (((4 + g) ^ sl) * 8)];
        }
#pragma unroll
        for (int n = 0; n < 4; n++) {
            const int rbase = (wc + n * 16 + fr) * 64;
            bf[n][0] = *(const s16x8*)&Bs[rbase + ((g ^ sl) * 8)];
            bf[n][1] = *(const s16x8*)&Bs[rbase + (((4 + g) ^ sl) * 8)];
        }
#pragma unroll
        for (int m = 0; m < 4; m++)
#pragma unroll
            for (int n = 0; n < 4; n++) {
                acc[m][n] = __builtin_amdgcn_mfma_f32_16x16x32_bf16(af[m][0], bf[n][0], acc[m][n], 0, 0, 0);
                acc[m][n] = __builtin_amdgcn_mfma_f32_16x16x32_bf16(af[m][1], bf[n][1], acc[m][n], 0, 0, 0);
            }
        __syncthreads();
    }

    const int fq = (l >> 4) * 4;
#pragma unroll
    for (int m = 0; m < 4; m++) {
#pragma unroll
        for (int n = 0; n < 4; n++) {
            const int col = tn + wc + n * 16 + fr;
            const float bv = bias[col];
            if (MODE == 3 && col >= 1536) {
                const int row0 = tm + wr + m * 16 + fq;
                const int bb = row0 >> 10;
                const int nseq = row0 & 1023;
                s16x4 ov;
#pragma unroll
                for (int j = 0; j < 4; j++) ov[j] = f2bf(acc[m][n][j] + bv);
                *(s16x4*)(vtout + (((size_t)(bb * 768 + (col - 1536))) << 10) + nseq) = ov;
            } else {
#pragma unroll
                for (int j = 0; j < 4; j++) {
                    const int row = tm + wr + m * 16 + fq + j;
                    float v = acc[m][n][j] + bv;
                    if (MODE == 2) {
                        const float u = v * (0.7978845608f + 0.0356774081f * v * v);
                        const float e = __builtin_amdgcn_exp2f(u * 2.8853900817779268f);
                        v = v - v * __builtin_amdgcn_rcpf(e + 1.0f);
                    }
                    ((short*)out)[(size_t)row * N + col] = f2bf(v);
                }
            }
        }
    }
}

// ---------------- GEMM db BN=64:
// TMODE 0 (proj): res f32 (x), out bf16 trunk = acc + bias + res
// TMODE 1 (fc2):  res bf16 trunk, out f32 final = acc + bias + res
#define G_STAGE(AS, BS)                                                     \
    {                                                                       \
        _Pragma("unroll") for (int c = 0; c < 4; c++) {                     \
            gload16(aP[c], &AS[(w * 4 + c) * 512]); aP[c] += 64;            \
        }                                                                   \
        _Pragma("unroll") for (int c = 0; c < 2; c++) {                     \
            gload16(bP[c], &BS[(w * 2 + c) * 512]); bP[c] += 64;            \
        }                                                                   \
    }

#define G_COMPUTE(AS, BS)                                                   \
    {                                                                       \
        s16x8 gaf[4][2], gbf[2][2];                                         \
        _Pragma("unroll") for (int m = 0; m < 4; m++) {                     \
            const int rbase = (wr + m * 16 + fr) * 64;                      \
            gaf[m][0] = *(const s16x8*)&AS[rbase + ((g ^ sl) * 8)];         \
            gaf[m][1] = *(const s16x8*)&AS[rbase + (((4 + g) ^ sl) * 8)];   \
        }                                                                   \
        _Pragma("unroll") for (int n = 0; n < 2; n++) {                     \
            const int rbase = (wc + n * 16 + fr) * 64;                      \
            gbf[n][0] = *(const s16x8*)&BS[rbase + ((g ^ sl) * 8)];         \
            gbf[n][1] = *(const s16x8*)&BS[rbase + (((4 + g) ^ sl) * 8)];   \
        }                                                                   \
        _Pragma("unroll") for (int m = 0; m < 4; m++)                       \
            _Pragma("unroll") for (int n = 0; n < 2; n++) {                 \
                acc[m][n] = __builtin_amdgcn_mfma_f32_16x16x32_bf16(gaf[m][0], gbf[n][0], acc[m][n], 0, 0, 0); \
                acc[m][n] = __builtin_amdgcn_mfma_f32_16x16x32_bf16(gaf[m][1], gbf[n][1], acc[m][n], 0, 0, 0); \
            }                                                               \
    }

template <int TMODE>
__global__ __launch_bounds__(256) void gemm_bt_db(
    const short* __restrict__ A, const short* __restrict__ Bt,
    const float* __restrict__ bias, const void* __restrict__ res,
    void* __restrict__ out, int M, int N, int K)
{
    __shared__ __align__(16) short As0[128 * 64];
    __shared__ __align__(16) short As1[128 * 64];
    __shared__ __align__(16) short Bs0[64 * 64];
    __shared__ __align__(16) short Bs1[64 * 64];

    const int t = threadIdx.x;
    const int l = t & 63;
    const int w = t >> 6;
    const int wr = (w >> 1) * 64;
    const int wc = (w & 1) * 32;

    const int ncol = N >> 6;
    const int xcd = blockIdx.x & 7;
    const int idx = blockIdx.x >> 3;
    const int tn = (idx % ncol) << 6;
    const int tm = ((idx / ncol) * 8 + xcd) << 7;

    const int srow = l >> 3;
    const int scol = ((l & 7) ^ srow) * 8;
    const short* aP[4]; const short* bP[2];
#pragma unroll
    for (int c = 0; c < 4; c++)
        aP[c] = A  + (size_t)(tm + (w * 4 + c) * 8 + srow) * K + scol;
#pragma unroll
    for (int c = 0; c < 2; c++)
        bP[c] = Bt + (size_t)(tn + (w * 2 + c) * 8 + srow) * K + scol;

    const int fr = l & 15;
    const int g = l >> 4;
    const int sl = fr & 7;

    f32x4 acc[4][2] = {};

    G_STAGE(As0, Bs0);
    __syncthreads();

    const int half = K >> 7;
    for (int it = 0; it < half; ++it) {
        G_STAGE(As1, Bs1);
        G_COMPUTE(As0, Bs0);
        __syncthreads();
        if (it < half - 1) G_STAGE(As0, Bs0);
        G_COMPUTE(As1, Bs1);
        __syncthreads();
    }

    const int fq = g * 4;
#pragma unroll
    for (int m = 0; m < 4; m++) {
#pragma unroll
        for (int n = 0; n < 2; n++) {
            const int col = tn + wc + n * 16 + fr;
            const float bv = bias[col];
#pragma unroll
            for (int j = 0; j < 4; j++) {
                const int row = tm + wr + m * 16 + fq + j;
                const size_t off = (size_t)row * N + col;
                if (TMODE == 0) {
                    ((short*)out)[off] = f2bf(acc[m][n][j] + bv + ((const float*)res)[off]);
                } else {
                    ((float*)out)[off] = acc[m][n][j] + bv + bf2f(((const short*)res)[off]);
                }
            }
        }
    }
}

// ---------------- Flash attention v8 (setprio around MFMA clusters)
#define ATTN_STAGE(KS, VS)                                                  \
    {                                                                       \
        gload16(kP,                    &KS[w * 1024]);                      \
        gload16(kP + (size_t)8 * 2304, &KS[w * 1024 + 512]);                \
        gload16(vP,                    &VS[w * 1024]);                      \
        gload16(vP + (size_t)8 * 1024, &VS[w * 1024 + 512]);                \
        kP += (size_t)64 * 2304;                                            \
        vP += 64;                                                           \
    }

#define ATTN_COMPUTE(KS, VS)                                                \
    {                                                                       \
        s16x8 ka[4][2];                                                     \
        _Pragma("unroll") for (int n = 0; n < 4; n++) {                     \
            const int rbase = (n * 16 + lq) * 64;                           \
            ka[n][0] = *(const s16x8*)&KS[rbase + ((g * 8) ^ swz)];         \
            ka[n][1] = *(const s16x8*)&KS[rbase + ((32 + g * 8) ^ swz)];    \
        }                                                                   \
        f32x4 s[2][4];                                                      \
        __builtin_amdgcn_s_setprio(1);                                      \
        _Pragma("unroll") for (int r = 0; r < 2; r++)                       \
            _Pragma("unroll") for (int n = 0; n < 4; n++) {                 \
                f32x4 sv = {};                                              \
                sv = __builtin_amdgcn_mfma_f32_16x16x32_bf16(ka[n][0], qb[r][0], sv, 0, 0, 0); \
                sv = __builtin_amdgcn_mfma_f32_16x16x32_bf16(ka[n][1], qb[r][1], sv, 0, 0, 0); \
                s[r][n] = sv;                                               \
            }                                                               \
        __builtin_amdgcn_s_setprio(0);                                      \
        s16x8 va[4][2];                                                     \
        _Pragma("unroll") for (int dt = 0; dt < 4; dt++) {                  \
            const int rbase = (dt * 16 + lq) * 64;                          \
            va[dt][0] = *(const s16x8*)&VS[rbase + ((g * 8) ^ swz)];        \
            va[dt][1] = *(const s16x8*)&VS[rbase + ((32 + g * 8) ^ swz)];   \
        }                                                                   \
        _Pragma("unroll") for (int r = 0; r < 2; r++) {                     \
            float mx = fmaxf(fmaxf(s[r][0][0], s[r][0][1]), fmaxf(s[r][0][2], s[r][0][3])); \
            _Pragma("unroll") for (int n = 1; n < 4; n++)                   \
                mx = fmaxf(mx, fmaxf(fmaxf(s[r][n][0], s[r][n][1]), fmaxf(s[r][n][2], s[r][n][3]))); \
            const float mxs = mx * kSc;                                     \
            if (!__all(mxs - m_run[r] <= 8.0f)) {                           \
                float gm = mxs;                                             \
                gm = fmaxf(gm, __shfl_xor(gm, 16, 64));                     \
                gm = fmaxf(gm, __shfl_xor(gm, 32, 64));                     \
                const float mnew = fmaxf(m_run[r], gm);                     \
                const float alpha = __builtin_amdgcn_exp2f(m_run[r] - mnew);\
                m_run[r] = mnew;                                            \
                l_run[r] *= alpha;                                          \
                _Pragma("unroll") for (int dt = 0; dt < 4; dt++) {          \
                    acc[r][dt][0] *= alpha; acc[r][dt][1] *= alpha;         \
                    acc[r][dt][2] *= alpha; acc[r][dt][3] *= alpha;         \
                }                                                           \
            }                                                               \
            const float mb = m_run[r];                                      \
            float ssum = 0.f;                                               \
            _Pragma("unroll") for (int n = 0; n < 4; n++) {                 \
                const float p0 = __builtin_amdgcn_exp2f(s[r][n][0] * kSc - mb); \
                const float p1 = __builtin_amdgcn_exp2f(s[r][n][1] * kSc - mb); \
                const float p2 = __builtin_amdgcn_exp2f(s[r][n][2] * kSc - mb); \
                const float p3 = __builtin_amdgcn_exp2f(s[r][n][3] * kSc - mb); \
                ssum += (p0 + p1) + (p2 + p3);                              \
                unsigned lo, hi;                                            \
                asm("v_cvt_pk_bf16_f32 %0, %1, %2" : "=v"(lo) : "v"(p0), "v"(p1)); \
                asm("v_cvt_pk_bf16_f32 %0, %1, %2" : "=v"(hi) : "v"(p2), "v"(p3)); \
                unsigned* pp = (unsigned*)&Ps[w][r * 16 + lq][n * 16 + g * 4]; \
                pp[0] = lo; pp[1] = hi;                                     \
            }                                                               \
            l_run[r] += ssum;                                               \
        }                                                                   \
        __builtin_amdgcn_s_setprio(1);                                      \
        _Pragma("unroll") for (int r = 0; r < 2; r++) {                     \
            const s16x8 pb0 = *(const s16x8*)&Ps[w][r * 16 + lq][g * 8];    \
            const s16x8 pb1 = *(const s16x8*)&Ps[w][r * 16 + lq][32 + g * 8]; \
            _Pragma("unroll") for (int dt = 0; dt < 4; dt++) {              \
                acc[r][dt] = __builtin_amdgcn_mfma_f32_16x16x32_bf16(va[dt][0], pb0, acc[r][dt], 0, 0, 0); \
                acc[r][dt] = __builtin_amdgcn_mfma_f32_16x16x32_bf16(va[dt][1], pb1, acc[r][dt], 0, 0, 0); \
            }                                                               \
        }                                                                   \
        __builtin_amdgcn_s_setprio(0);                                      \
    }

__global__ __launch_bounds__(256) void attn_kernel(
    const short* __restrict__ qkv, const short* __restrict__ vTg,
    short* __restrict__ out)
{
    const int bid = blockIdx.x;
    const int x = bid & 7;
    const int i = bid >> 3;            // 0..95
    const int bh = x + 8 * (i % 12);   // 0..95
    const int qt = i / 12;             // 0..7
    const int b = bh / 12, h = bh % 12;

    __shared__ __align__(16) short Ks0[64 * 64];
    __shared__ __align__(16) short Ks1[64 * 64];
    __shared__ __align__(16) short Vs0[64 * 64];
    __shared__ __align__(16) short Vs1[64 * 64];
    __shared__ __align__(16) short Ps[4][32][72];

    const int t = threadIdx.x;
    const int l = t & 63;
    const int w = t >> 6;
    const int lq = l & 15;
    const int g = l >> 4;
    const float kSc = 0.18033688011112042f;  // 0.125 * log2(e)

    const int q0 = b * 1024 + qt * 128 + w * 32;

    s16x8 qb[2][2];
#pragma unroll
    for (int r = 0; r < 2; r++) {
        const short* qp = qkv + ((size_t)(q0 + r * 16 + lq)) * 2304 + h * 64 + g * 8;
        qb[r][0] = *(const s16x8*)qp;
        qb[r][1] = *(const s16x8*)(qp + 32);
    }

    const int srow = l >> 3;
    const int scol = ((l & 7) ^ srow) * 8;
    const short* kP = qkv + (size_t)(b * 1024 + w * 16 + srow) * 2304 + 768 + h * 64 + scol;
    const short* vP = vTg + (size_t)(bh * 64 + w * 16 + srow) * 1024 + scol;

    f32x4 acc[2][4] = {};
    float m_run[2] = {-1e30f, -1e30f};
    float l_run[2] = {0.f, 0.f};

    const int swz = (lq & 7) * 8;

    ATTN_STAGE(Ks0, Vs0);
    __syncthreads();

    for (int it = 0; it < 8; ++it) {
        ATTN_STAGE(Ks1, Vs1);
        ATTN_COMPUTE(Ks0, Vs0);
        __syncthreads();
        if (it < 7) ATTN_STAGE(Ks0, Vs0);
        ATTN_COMPUTE(Ks1, Vs1);
        __syncthreads();
    }

#pragma unroll
    for (int r = 0; r < 2; r++) {
        float ls = l_run[r];
        ls += __shfl_xor(ls, 16, 64);
        ls += __shfl_xor(ls, 32, 64);
        const float rinv = 1.0f / ls;
        const int qrow = q0 + r * 16 + lq;
#pragma unroll
        for (int dt = 0; dt < 4; dt++) {
            s16x4 ov;
#pragma unroll
            for (int j = 0; j < 4; j++) ov[j] = f2bf(acc[r][dt][j] * rinv);
            *(s16x4*)(out + (size_t)qrow * 768 + h * 64 + dt * 16 + g * 4) = ov;
        }
    }
}

extern "C" void kernel_launch(void* const* d_in, const int* in_sizes, int n_in,
                              void* d_out, int out_size, void* d_ws, size_t ws_size,
                              hipStream_t stream) {
    const float* x      = (const float*)d_in[0];
    const float* n1g    = (const float*)d_in[1];
    const float* n1b    = (const float*)d_in[2];
    const float* qkv_w  = (const float*)d_in[3];
    const float* qkv_b  = (const float*)d_in[4];
    const float* proj_w = (const float*)d_in[5];
    const float* proj_b = (const float*)d_in[6];
    const float* n2g    = (const float*)d_in[7];
    const float* n2b    = (const float*)d_in[8];
    const float* fc1_w  = (const float*)d_in[9];
    const float* fc1_b  = (const float*)d_in[10];
    const float* fc2_w  = (const float*)d_in[11];
    const float* fc2_b  = (const float*)d_in[12];
    float* out = (float*)d_out;

    char* ws = (char*)d_ws;
    short* qkv_wT  = (short*)(ws + 0);           // [2304][768] bf16
    short* proj_wT = (short*)(ws + 3538944);     // [768][768]
    short* fc1_wT  = (short*)(ws + 4718592);     // [3072][768]
    short* fc2_wT  = (short*)(ws + 9437184);     // [768][3072]
    short* bufA    = (short*)(ws + 14155776);    // 8192x768 bf16 (ln1/attn_out/ln2)
    short* bufB    = (short*)(ws + 26738688);    // 8192x3072 bf16 (qkv / h1)
    short* vT      = (short*)(ws + 64487424);    // 96x64x1024 bf16
    short* trunk   = (short*)(ws + 77070336);    // 8192x768 bf16 (x1 residual)

    prep_all<<<8192 + 6912, 256, 0, stream>>>(
        x, n1g, n1b, bufA,
        qkv_w, proj_w, fc1_w, fc2_w, qkv_wT, proj_wT, fc1_wT, fc2_wT);

    gemm_bt<3><<<64 * (2304 / 128), 256, 0, stream>>>(
        bufA, qkv_wT, qkv_b, nullptr, bufB, vT, 8192, 2304, 768);

    attn_kernel<<<768, 256, 0, stream>>>(bufB, vT, bufA);

    gemm_bt_db<0><<<64 * (768 / 64), 256, 0, stream>>>(
        bufA, proj_wT, proj_b, x, trunk, 8192, 768, 768);

    layernorm_bf16<<<8192, 192, 0, stream>>>(trunk, n2g, n2b, bufA);

    gemm_bt<2><<<64 * (3072 / 128), 256, 0, stream>>>(
        bufA, fc1_wT, fc1_b, nullptr, bufB, nullptr, 8192, 3072, 768);

    gemm_bt_db<1><<<64 * (768 / 64), 256, 0, stream>>>(
        bufB, fc2_wT, fc2_b, trunk, out, 8192, 768, 3072);
}

// Round 21
// 225.343 us; speedup vs baseline: 1.0631x; 1.0270x over previous
//
#include <hip/hip_runtime.h>

typedef __attribute__((ext_vector_type(8))) short s16x8;
typedef __attribute__((ext_vector_type(4))) short s16x4;
typedef __attribute__((ext_vector_type(4))) float f32x4;

static __device__ __forceinline__ short f2bf(float f) {
    unsigned u = __builtin_bit_cast(unsigned, f);
    u = (u + 0x7FFFu + ((u >> 16) & 1u)) >> 16;
    return (short)u;
}
static __device__ __forceinline__ float bf2f(short h) {
    unsigned u = ((unsigned)(unsigned short)h) << 16;
    return __builtin_bit_cast(float, u);
}

__device__ __forceinline__ void gload16(const short* g, short* l) {
    __builtin_amdgcn_global_load_lds(
        (const __attribute__((address_space(1))) void*)g,
        (__attribute__((address_space(3))) void*)l,
        16, 0, 0);
}

// ---------------- prep: LN1 rows + all 4 weight transposes in ONE launch
__device__ __forceinline__ void tc_tile(
    const float* __restrict__ W, short* __restrict__ Wt, int K, int N,
    int bx, int by, int tx, int ty)
{
    __shared__ float tile[32][33];
    for (int i = 0; i < 32; i += 8)
        tile[ty + i][tx] = W[(size_t)(by + ty + i) * N + bx + tx];
    __syncthreads();
    for (int i = 0; i < 32; i += 8)
        Wt[(size_t)(bx + ty + i) * K + by + tx] = f2bf(tile[tx][ty + i]);
}

__device__ __forceinline__ void ln_row(
    const float* __restrict__ x, const float* __restrict__ g,
    const float* __restrict__ b, short* __restrict__ out, int row, int t)
{
    __shared__ float red[4];
    const float* xr = x + (size_t)row * 768;
    float v0 = xr[t], v1 = xr[t + 256], v2 = xr[t + 512];
    float s = v0 + v1 + v2;
    for (int off = 32; off >= 1; off >>= 1) s += __shfl_down(s, off, 64);
    if ((t & 63) == 0) red[t >> 6] = s;
    __syncthreads();
    const float mean = (red[0] + red[1] + red[2] + red[3]) * (1.0f / 768.0f);
    const float d0 = v0 - mean, d1 = v1 - mean, d2 = v2 - mean;
    __syncthreads();
    float ss = d0 * d0 + d1 * d1 + d2 * d2;
    for (int off = 32; off >= 1; off >>= 1) ss += __shfl_down(ss, off, 64);
    if ((t & 63) == 0) red[t >> 6] = ss;
    __syncthreads();
    const float var = (red[0] + red[1] + red[2] + red[3]) * (1.0f / 768.0f);
    const float rstd = rsqrtf(var + 1e-5f);
    out[(size_t)row * 768 + t]       = f2bf(d0 * rstd * g[t] + b[t]);
    out[(size_t)row * 768 + t + 256] = f2bf(d1 * rstd * g[t + 256] + b[t + 256]);
    out[(size_t)row * 768 + t + 512] = f2bf(d2 * rstd * g[t + 512] + b[t + 512]);
}

// blocks: 0..8191 LN1 | then qkv 1728 | proj 576 | fc1 2304 | fc2 2304
__global__ __launch_bounds__(256) void prep_all(
    const float* __restrict__ x, const float* __restrict__ n1g,
    const float* __restrict__ n1b, short* __restrict__ ln_out,
    const float* __restrict__ qkv_w, const float* __restrict__ proj_w,
    const float* __restrict__ fc1_w, const float* __restrict__ fc2_w,
    short* __restrict__ qkv_wT, short* __restrict__ proj_wT,
    short* __restrict__ fc1_wT, short* __restrict__ fc2_wT)
{
    const int t = threadIdx.x;
    int bid = blockIdx.x;
    if (bid < 8192) { ln_row(x, n1g, n1b, ln_out, bid, t); return; }
    bid -= 8192;
    const int tx = t & 31, ty = t >> 5;
    if (bid < 1728) {
        tc_tile(qkv_w, qkv_wT, 768, 2304, (bid % 72) * 32, (bid / 72) * 32, tx, ty);
    } else if (bid < 2304) {
        bid -= 1728;
        tc_tile(proj_w, proj_wT, 768, 768, (bid % 24) * 32, (bid / 24) * 32, tx, ty);
    } else if (bid < 4608) {
        bid -= 2304;
        tc_tile(fc1_w, fc1_wT, 768, 3072, (bid % 96) * 32, (bid / 96) * 32, tx, ty);
    } else {
        bid -= 4608;
        tc_tile(fc2_w, fc2_wT, 3072, 768, (bid % 24) * 32, (bid / 24) * 32, tx, ty);
    }
}

// ---------------- LayerNorm over bf16 trunk (LN2): 192 threads, ushort4 loads
__global__ __launch_bounds__(192) void layernorm_bf16(
    const short* __restrict__ x, const float* __restrict__ g,
    const float* __restrict__ b, short* __restrict__ out)
{
    __shared__ float red[3];
    const int row = blockIdx.x;
    const int t = threadIdx.x;           // 0..191, covers 4 elems each
    const s16x4 v = *(const s16x4*)(x + (size_t)row * 768 + t * 4);
    float f0 = bf2f(v[0]), f1 = bf2f(v[1]), f2 = bf2f(v[2]), f3 = bf2f(v[3]);

    float s = (f0 + f1) + (f2 + f3);
    for (int off = 32; off >= 1; off >>= 1) s += __shfl_down(s, off, 64);
    if ((t & 63) == 0) red[t >> 6] = s;
    __syncthreads();
    const float mean = (red[0] + red[1] + red[2]) * (1.0f / 768.0f);
    const float d0 = f0 - mean, d1 = f1 - mean, d2 = f2 - mean, d3 = f3 - mean;
    __syncthreads();
    float ss = (d0 * d0 + d1 * d1) + (d2 * d2 + d3 * d3);
    for (int off = 32; off >= 1; off >>= 1) ss += __shfl_down(ss, off, 64);
    if ((t & 63) == 0) red[t >> 6] = ss;
    __syncthreads();
    const float var = (red[0] + red[1] + red[2]) * (1.0f / 768.0f);
    const float rstd = rsqrtf(var + 1e-5f);
    s16x4 o;
    o[0] = f2bf(d0 * rstd * g[t * 4 + 0] + b[t * 4 + 0]);
    o[1] = f2bf(d1 * rstd * g[t * 4 + 1] + b[t * 4 + 1]);
    o[2] = f2bf(d2 * rstd * g[t * 4 + 2] + b[t * 4 + 2]);
    o[3] = f2bf(d3 * rstd * g[t * 4 + 3] + b[t * 4 + 3]);
    *(s16x4*)(out + (size_t)row * 768 + t * 4) = o;
}

// ---------------- GEMM (single-buffered, BN=128, K templated & fully
// unrolled): BK=64, XOR-swizzled LDS, XCD-affine flat grid.
// MODE 2: out bf16 = gelu_tanh(acc + bias)
// MODE 3: QKV: cols<1536 -> bf16 out; cols>=1536 (V) -> vtout[bh*64+d][n] s16x4
template <int MODE, int KK>
__global__ __launch_bounds__(256) void gemm_bt(
    const short* __restrict__ A, const short* __restrict__ Bt,
    const float* __restrict__ bias, const float* __restrict__ res,
    void* __restrict__ out, short* __restrict__ vtout, int M, int N)
{
    __shared__ __align__(16) short As[128 * 64];
    __shared__ __align__(16) short Bs[128 * 64];

    const int t = threadIdx.x;
    const int l = t & 63;
    const int w = t >> 6;
    const int wr = (w >> 1) * 64;
    const int wc = (w & 1) * 64;

    const int ncol = N >> 7;
    const int xcd = blockIdx.x & 7;
    const int idx = blockIdx.x >> 3;
    const int tn = (idx % ncol) << 7;
    const int tm = ((idx / ncol) * 8 + xcd) << 7;

    const int srow = l >> 3;                  // 0..7 within chunk
    const int scol = ((l & 7) ^ srow) * 8;    // pre-swizzled col (shorts)
    const short* aS[4]; const short* bS[4];
#pragma unroll
    for (int c = 0; c < 4; c++) {
        aS[c] = A  + (size_t)(tm + (w * 4 + c) * 8 + srow) * KK + scol;
        bS[c] = Bt + (size_t)(tn + (w * 4 + c) * 8 + srow) * KK + scol;
    }

    const int fr = l & 15;
    const int g = l >> 4;
    const int sl = fr & 7;            // row component of the XOR swizzle

    f32x4 acc[4][4] = {};

#pragma unroll
    for (int k0 = 0; k0 < KK; k0 += 64) {
#pragma unroll
        for (int c = 0; c < 4; c++) {
            gload16(aS[c] + k0, &As[(w * 4 + c) * 512]);
            gload16(bS[c] + k0, &Bs[(w * 4 + c) * 512]);
        }
        __syncthreads();

        s16x8 af[4][2], bf[4][2];
#pragma unroll
        for (int m = 0; m < 4; m++) {
            const int rbase = (wr + m * 16 + fr) * 64;
            af[m][0] = *(const s16x8*)&As[rbase + ((g ^ sl) * 8)];
            af[m][1] = *(const s16x8*)&As[rbase + (((4 + g) ^ sl) * 8)];
        }
#pragma unroll
        for (int n = 0; n < 4; n++) {
            const int rbase = (wc + n * 16 + fr) * 64;
            bf[n][0] = *(const s16x8*)&Bs[rbase + ((g ^ sl) * 8)];
            bf[n][1] = *(const s16x8*)&Bs[rbase + (((4 + g) ^ sl) * 8)];
        }
#pragma unroll
        for (int m = 0; m < 4; m++)
#pragma unroll
            for (int n = 0; n < 4; n++) {
                acc[m][n] = __builtin_amdgcn_mfma_f32_16x16x32_bf16(af[m][0], bf[n][0], acc[m][n], 0, 0, 0);
                acc[m][n] = __builtin_amdgcn_mfma_f32_16x16x32_bf16(af[m][1], bf[n][1], acc[m][n], 0, 0, 0);
            }
        __syncthreads();
    }

    const int fq = (l >> 4) * 4;
#pragma unroll
    for (int m = 0; m < 4; m++) {
#pragma unroll
        for (int n = 0; n < 4; n++) {
            const int col = tn + wc + n * 16 + fr;
            const float bv = bias[col];
            if (MODE == 3 && col >= 1536) {
                const int row0 = tm + wr + m * 16 + fq;
                const int bb = row0 >> 10;
                const int nseq = row0 & 1023;
                s16x4 ov;
#pragma unroll
                for (int j = 0; j < 4; j++) ov[j] = f2bf(acc[m][n][j] + bv);
                *(s16x4*)(vtout + (((size_t)(bb * 768 + (col - 1536))) << 10) + nseq) = ov;
            } else {
#pragma unroll
                for (int j = 0; j < 4; j++) {
                    const int row = tm + wr + m * 16 + fq + j;
                    float v = acc[m][n][j] + bv;
                    if (MODE == 2) {
                        const float u = v * (0.7978845608f + 0.0356774081f * v * v);
                        const float e = __builtin_amdgcn_exp2f(u * 2.8853900817779268f);
                        v = v - v * __builtin_amdgcn_rcpf(e + 1.0f);
                    }
                    ((short*)out)[(size_t)row * N + col] = f2bf(v);
                }
            }
        }
    }
}

// ---------------- GEMM db BN=64:
// TMODE 0 (proj): res f32 (x), out bf16 trunk = acc + bias + res
// TMODE 1 (fc2):  res bf16 trunk, out f32 final = acc + bias + res
#define G_STAGE(AS, BS)                                                     \
    {                                                                       \
        _Pragma("unroll") for (int c = 0; c < 4; c++) {                     \
            gload16(aP[c], &AS[(w * 4 + c) * 512]); aP[c] += 64;            \
        }                                                                   \
        _Pragma("unroll") for (int c = 0; c < 2; c++) {                     \
            gload16(bP[c], &BS[(w * 2 + c) * 512]); bP[c] += 64;            \
        }                                                                   \
    }

#define G_COMPUTE(AS, BS)                                                   \
    {                                                                       \
        s16x8 gaf[4][2], gbf[2][2];                                         \
        _Pragma("unroll") for (int m = 0; m < 4; m++) {                     \
            const int rbase = (wr + m * 16 + fr) * 64;                      \
            gaf[m][0] = *(const s16x8*)&AS[rbase + ((g ^ sl) * 8)];         \
            gaf[m][1] = *(const s16x8*)&AS[rbase + (((4 + g) ^ sl) * 8)];   \
        }                                                                   \
        _Pragma("unroll") for (int n = 0; n < 2; n++) {                     \
            const int rbase = (wc + n * 16 + fr) * 64;                      \
            gbf[n][0] = *(const s16x8*)&BS[rbase + ((g ^ sl) * 8)];         \
            gbf[n][1] = *(const s16x8*)&BS[rbase + (((4 + g) ^ sl) * 8)];   \
        }                                                                   \
        _Pragma("unroll") for (int m = 0; m < 4; m++)                       \
            _Pragma("unroll") for (int n = 0; n < 2; n++) {                 \
                acc[m][n] = __builtin_amdgcn_mfma_f32_16x16x32_bf16(gaf[m][0], gbf[n][0], acc[m][n], 0, 0, 0); \
                acc[m][n] = __builtin_amdgcn_mfma_f32_16x16x32_bf16(gaf[m][1], gbf[n][1], acc[m][n], 0, 0, 0); \
            }                                                               \
    }

template <int TMODE>
__global__ __launch_bounds__(256) void gemm_bt_db(
    const short* __restrict__ A, const short* __restrict__ Bt,
    const float* __restrict__ bias, const void* __restrict__ res,
    void* __restrict__ out, int M, int N, int K)
{
    __shared__ __align__(16) short As0[128 * 64];
    __shared__ __align__(16) short As1[128 * 64];
    __shared__ __align__(16) short Bs0[64 * 64];
    __shared__ __align__(16) short Bs1[64 * 64];

    const int t = threadIdx.x;
    const int l = t & 63;
    const int w = t >> 6;
    const int wr = (w >> 1) * 64;
    const int wc = (w & 1) * 32;

    const int ncol = N >> 6;
    const int xcd = blockIdx.x & 7;
    const int idx = blockIdx.x >> 3;
    const int tn = (idx % ncol) << 6;
    const int tm = ((idx / ncol) * 8 + xcd) << 7;

    const int srow = l >> 3;
    const int scol = ((l & 7) ^ srow) * 8;
    const short* aP[4]; const short* bP[2];
#pragma unroll
    for (int c = 0; c < 4; c++)
        aP[c] = A  + (size_t)(tm + (w * 4 + c) * 8 + srow) * K + scol;
#pragma unroll
    for (int c = 0; c < 2; c++)
        bP[c] = Bt + (size_t)(tn + (w * 2 + c) * 8 + srow) * K + scol;

    const int fr = l & 15;
    const int g = l >> 4;
    const int sl = fr & 7;

    f32x4 acc[4][2] = {};

    G_STAGE(As0, Bs0);
    __syncthreads();

    const int half = K >> 7;
    for (int it = 0; it < half; ++it) {
        G_STAGE(As1, Bs1);
        G_COMPUTE(As0, Bs0);
        __syncthreads();
        if (it < half - 1) G_STAGE(As0, Bs0);
        G_COMPUTE(As1, Bs1);
        __syncthreads();
    }

    const int fq = g * 4;
#pragma unroll
    for (int m = 0; m < 4; m++) {
#pragma unroll
        for (int n = 0; n < 2; n++) {
            const int col = tn + wc + n * 16 + fr;
            const float bv = bias[col];
#pragma unroll
            for (int j = 0; j < 4; j++) {
                const int row = tm + wr + m * 16 + fq + j;
                const size_t off = (size_t)row * N + col;
                if (TMODE == 0) {
                    ((short*)out)[off] = f2bf(acc[m][n][j] + bv + ((const float*)res)[off]);
                } else {
                    ((float*)out)[off] = acc[m][n][j] + bv + bf2f(((const short*)res)[off]);
                }
            }
        }
    }
}

// ---------------- Flash attention v8 (setprio around MFMA clusters)
#define ATTN_STAGE(KS, VS)                                                  \
    {                                                                       \
        gload16(kP,                    &KS[w * 1024]);                      \
        gload16(kP + (size_t)8 * 2304, &KS[w * 1024 + 512]);                \
        gload16(vP,                    &VS[w * 1024]);                      \
        gload16(vP + (size_t)8 * 1024, &VS[w * 1024 + 512]);                \
        kP += (size_t)64 * 2304;                                            \
        vP += 64;                                                           \
    }

#define ATTN_COMPUTE(KS, VS)                                                \
    {                                                                       \
        s16x8 ka[4][2];                                                     \
        _Pragma("unroll") for (int n = 0; n < 4; n++) {                     \
            const int rbase = (n * 16 + lq) * 64;                           \
            ka[n][0] = *(const s16x8*)&KS[rbase + ((g * 8) ^ swz)];         \
            ka[n][1] = *(const s16x8*)&KS[rbase + ((32 + g * 8) ^ swz)];    \
        }                                                                   \
        f32x4 s[2][4];                                                      \
        __builtin_amdgcn_s_setprio(1);                                      \
        _Pragma("unroll") for (int r = 0; r < 2; r++)                       \
            _Pragma("unroll") for (int n = 0; n < 4; n++) {                 \
                f32x4 sv = {};                                              \
                sv = __builtin_amdgcn_mfma_f32_16x16x32_bf16(ka[n][0], qb[r][0], sv, 0, 0, 0); \
                sv = __builtin_amdgcn_mfma_f32_16x16x32_bf16(ka[n][1], qb[r][1], sv, 0, 0, 0); \
                s[r][n] = sv;                                               \
            }                                                               \
        __builtin_amdgcn_s_setprio(0);                                      \
        s16x8 va[4][2];                                                     \
        _Pragma("unroll") for (int dt = 0; dt < 4; dt++) {                  \
            const int rbase = (dt * 16 + lq) * 64;                          \
            va[dt][0] = *(const s16x8*)&VS[rbase + ((g * 8) ^ swz)];        \
            va[dt][1] = *(const s16x8*)&VS[rbase + ((32 + g * 8) ^ swz)];   \
        }                                                                   \
        _Pragma("unroll") for (int r = 0; r < 2; r++) {                     \
            float mx = fmaxf(fmaxf(s[r][0][0], s[r][0][1]), fmaxf(s[r][0][2], s[r][0][3])); \
            _Pragma("unroll") for (int n = 1; n < 4; n++)                   \
                mx = fmaxf(mx, fmaxf(fmaxf(s[r][n][0], s[r][n][1]), fmaxf(s[r][n][2], s[r][n][3]))); \
            const float mxs = mx * kSc;                                     \
            if (!__all(mxs - m_run[r] <= 8.0f)) {                           \
                float gm = mxs;                                             \
                gm = fmaxf(gm, __shfl_xor(gm, 16, 64));                     \
                gm = fmaxf(gm, __shfl_xor(gm, 32, 64));                     \
                const float mnew = fmaxf(m_run[r], gm);                     \
                const float alpha = __builtin_amdgcn_exp2f(m_run[r] - mnew);\
                m_run[r] = mnew;                                            \
                l_run[r] *= alpha;                                          \
                _Pragma("unroll") for (int dt = 0; dt < 4; dt++) {          \
                    acc[r][dt][0] *= alpha; acc[r][dt][1] *= alpha;         \
                    acc[r][dt][2] *= alpha; acc[r][dt][3] *= alpha;         \
                }                                                           \
            }                                                               \
            const float mb = m_run[r];                                      \
            float ssum = 0.f;                                               \
            _Pragma("unroll") for (int n = 0; n < 4; n++) {                 \
                const float p0 = __builtin_amdgcn_exp2f(s[r][n][0] * kSc - mb); \
                const float p1 = __builtin_amdgcn_exp2f(s[r][n][1] * kSc - mb); \
                const float p2 = __builtin_amdgcn_exp2f(s[r][n][2] * kSc - mb); \
                const float p3 = __builtin_amdgcn_exp2f(s[r][n][3] * kSc - mb); \
                ssum += (p0 + p1) + (p2 + p3);                              \
                unsigned lo, hi;                                            \
                asm("v_cvt_pk_bf16_f32 %0, %1, %2" : "=v"(lo) : "v"(p0), "v"(p1)); \
                asm("v_cvt_pk_bf16_f32 %0, %1, %2" : "=v"(hi) : "v"(p2), "v"(p3)); \
                unsigned* pp = (unsigned*)&Ps[w][r * 16 + lq][n * 16 + g * 4]; \
                pp[0] = lo; pp[1] = hi;                                     \
            }                                                               \
            l_run[r] += ssum;                                               \
        }                                                                   \
        __builtin_amdgcn_s_setprio(1);                                      \
        _Pragma("unroll") for (int r = 0; r < 2; r++) {                     \
            const s16x8 pb0 = *(const s16x8*)&Ps[w][r * 16 + lq][g * 8];    \
            const s16x8 pb1 = *(const s16x8*)&Ps[w][r * 16 + lq][32 + g * 8]; \
            _Pragma("unroll") for (int dt = 0; dt < 4; dt++) {              \
                acc[r][dt] = __builtin_amdgcn_mfma_f32_16x16x32_bf16(va[dt][0], pb0, acc[r][dt], 0, 0, 0); \
                acc[r][dt] = __builtin_amdgcn_mfma_f32_16x16x32_bf16(va[dt][1], pb1, acc[r][dt], 0, 0, 0); \
            }                                                               \
        }                                                                   \
        __builtin_amdgcn_s_setprio(0);                                      \
    }

__global__ __launch_bounds__(256) void attn_kernel(
    const short* __restrict__ qkv, const short* __restrict__ vTg,
    short* __restrict__ out)
{
    const int bid = blockIdx.x;
    const int x = bid & 7;
    const int i = bid >> 3;            // 0..95
    const int bh = x + 8 * (i % 12);   // 0..95
    const int qt = i / 12;             // 0..7
    const int b = bh / 12, h = bh % 12;

    __shared__ __align__(16) short Ks0[64 * 64];
    __shared__ __align__(16) short Ks1[64 * 64];
    __shared__ __align__(16) short Vs0[64 * 64];
    __shared__ __align__(16) short Vs1[64 * 64];
    __shared__ __align__(16) short Ps[4][32][72];

    const int t = threadIdx.x;
    const int l = t & 63;
    const int w = t >> 6;
    const int lq = l & 15;
    const int g = l >> 4;
    const float kSc = 0.18033688011112042f;  // 0.125 * log2(e)

    const int q0 = b * 1024 + qt * 128 + w * 32;

    s16x8 qb[2][2];
#pragma unroll
    for (int r = 0; r < 2; r++) {
        const short* qp = qkv + ((size_t)(q0 + r * 16 + lq)) * 2304 + h * 64 + g * 8;
        qb[r][0] = *(const s16x8*)qp;
        qb[r][1] = *(const s16x8*)(qp + 32);
    }

    const int srow = l >> 3;
    const int scol = ((l & 7) ^ srow) * 8;
    const short* kP = qkv + (size_t)(b * 1024 + w * 16 + srow) * 2304 + 768 + h * 64 + scol;
    const short* vP = vTg + (size_t)(bh * 64 + w * 16 + srow) * 1024 + scol;

    f32x4 acc[2][4] = {};
    float m_run[2] = {-1e30f, -1e30f};
    float l_run[2] = {0.f, 0.f};

    const int swz = (lq & 7) * 8;

    ATTN_STAGE(Ks0, Vs0);
    __syncthreads();

    for (int it = 0; it < 8; ++it) {
        ATTN_STAGE(Ks1, Vs1);
        ATTN_COMPUTE(Ks0, Vs0);
        __syncthreads();
        if (it < 7) ATTN_STAGE(Ks0, Vs0);
        ATTN_COMPUTE(Ks1, Vs1);
        __syncthreads();
    }

#pragma unroll
    for (int r = 0; r < 2; r++) {
        float ls = l_run[r];
        ls += __shfl_xor(ls, 16, 64);
        ls += __shfl_xor(ls, 32, 64);
        const float rinv = 1.0f / ls;
        const int qrow = q0 + r * 16 + lq;
#pragma unroll
        for (int dt = 0; dt < 4; dt++) {
            s16x4 ov;
#pragma unroll
            for (int j = 0; j < 4; j++) ov[j] = f2bf(acc[r][dt][j] * rinv);
            *(s16x4*)(out + (size_t)qrow * 768 + h * 64 + dt * 16 + g * 4) = ov;
        }
    }
}

extern "C" void kernel_launch(void* const* d_in, const int* in_sizes, int n_in,
                              void* d_out, int out_size, void* d_ws, size_t ws_size,
                              hipStream_t stream) {
    const float* x      = (const float*)d_in[0];
    const float* n1g    = (const float*)d_in[1];
    const float* n1b    = (const float*)d_in[2];
    const float* qkv_w  = (const float*)d_in[3];
    const float* qkv_b  = (const float*)d_in[4];
    const float* proj_w = (const float*)d_in[5];
    const float* proj_b = (const float*)d_in[6];
    const float* n2g    = (const float*)d_in[7];
    const float* n2b    = (const float*)d_in[8];
    const float* fc1_w  = (const float*)d_in[9];
    const float* fc1_b  = (const float*)d_in[10];
    const float* fc2_w  = (const float*)d_in[11];
    const float* fc2_b  = (const float*)d_in[12];
    float* out = (float*)d_out;

    char* ws = (char*)d_ws;
    short* qkv_wT  = (short*)(ws + 0);           // [2304][768] bf16
    short* proj_wT = (short*)(ws + 3538944);     // [768][768]
    short* fc1_wT  = (short*)(ws + 4718592);     // [3072][768]
    short* fc2_wT  = (short*)(ws + 9437184);     // [768][3072]
    short* bufA    = (short*)(ws + 14155776);    // 8192x768 bf16 (ln1/attn_out/ln2)
    short* bufB    = (short*)(ws + 26738688);    // 8192x3072 bf16 (qkv / h1)
    short* vT      = (short*)(ws + 64487424);    // 96x64x1024 bf16
    short* trunk   = (short*)(ws + 77070336);    // 8192x768 bf16 (x1 residual)

    prep_all<<<8192 + 6912, 256, 0, stream>>>(
        x, n1g, n1b, bufA,
        qkv_w, proj_w, fc1_w, fc2_w, qkv_wT, proj_wT, fc1_wT, fc2_wT);

    gemm_bt<3, 768><<<64 * (2304 / 128), 256, 0, stream>>>(
        bufA, qkv_wT, qkv_b, nullptr, bufB, vT, 8192, 2304);

    attn_kernel<<<768, 256, 0, stream>>>(bufB, vT, bufA);

    gemm_bt_db<0><<<64 * (768 / 64), 256, 0, stream>>>(
        bufA, proj_wT, proj_b, x, trunk, 8192, 768, 768);

    layernorm_bf16<<<8192, 192, 0, stream>>>(trunk, n2g, n2b, bufA);

    gemm_bt<2, 768><<<64 * (3072 / 128), 256, 0, stream>>>(
        bufA, fc1_wT, fc1_b, nullptr, bufB, nullptr, 8192, 3072);

    gemm_bt_db<1><<<64 * (768 / 64), 256, 0, stream>>>(
        bufB, fc2_wT, fc2_b, trunk, out, 8192, 768, 3072);
}